// Round 11
// baseline (203.954 us; speedup 1.0000x reference)
//
#include <hip/hip_runtime.h>
#include <stdint.h>

#define T_SEQ 2048
#define NB    2
#define DHD   128
#define NHQ   16
#define NHKV  4
#define SWIN  512
#define CDIM  2048
#define QKVN  3072

typedef __attribute__((ext_vector_type(8))) short short8;
typedef __attribute__((ext_vector_type(4))) float f32x4;
typedef __attribute__((ext_vector_type(16))) float f32x16;
typedef __attribute__((ext_vector_type(4))) unsigned int u32x4;
typedef __attribute__((address_space(3))) unsigned int lds_u32;
typedef __attribute__((address_space(1))) const unsigned int gbl_u32;

__device__ __forceinline__ unsigned short f2bf(float f) {
  unsigned int u = __float_as_uint(f);
  u += 0x7fffu + ((u >> 16) & 1u);
  return (unsigned short)(u >> 16);
}
__device__ __forceinline__ float bf2f(unsigned int h) {
  return __uint_as_float(h << 16);
}
__device__ __forceinline__ float exp2_fast(float x) {
  float r;
  asm("v_exp_f32 %0, %1" : "=v"(r) : "v"(x));
  return r;
}

// ---------------- fp32 -> bf16 for all three inputs, one launch ----------------
__global__ __launch_bounds__(256) void k_f2bf3(const float* __restrict__ a, unsigned short* __restrict__ oa, int na4,
                                               const float* __restrict__ b, unsigned short* __restrict__ ob, int nb4,
                                               const float* __restrict__ c, unsigned short* __restrict__ oc, int nc4) {
  const int n = na4 + nb4 + nc4;
  for (int i = blockIdx.x * 256 + threadIdx.x; i < n; i += gridDim.x * 256) {
    const float* src; unsigned short* dst; int j = i;
    if (j < na4) { src = a; dst = oa; }
    else if (j < na4 + nb4) { j -= na4; src = b; dst = ob; }
    else { j -= na4 + nb4; src = c; dst = oc; }
    float4 v = reinterpret_cast<const float4*>(src)[j];
    uint2 o;
    o.x = ((unsigned int)f2bf(v.y) << 16) | f2bf(v.x);
    o.y = ((unsigned int)f2bf(v.w) << 16) | f2bf(v.z);
    reinterpret_cast<uint2*>(dst)[j] = o;
  }
}

// ---------------- RoPE trig table ----------------
__global__ __launch_bounds__(256) void k_trig(float* __restrict__ tbl) {
  int i = blockIdx.x * 256 + threadIdx.x;
  if (i >= T_SEQ * 64) return;
  int t = i >> 6, f = i & 63;
  float invf = powf(10000.f, -(float)f * (1.f / 64.f));
  float ang = (float)t * invf;
  tbl[i] = cosf(ang);
  tbl[T_SEQ * 64 + i] = sinf(ang);
}

// ---------------- 256x256 8-phase GEMM (m201-faithful): C = A[M,K] x B[N,K]^T ----
// 8 waves (2Mx4N, 128x64/wave), BK=64, 2 LDS buffers x 64KB. Per K-tile 4 quadrant
// phases; each: {ds_read frags; stage 1 half-tile (2 gload_lds); barrier;
// lgkmcnt(0); setprio(1); 16 MFMA; setprio(0); [ph3: vmcnt(4)]; barrier}.
// Counted vmcnt never 0 mid-loop; stage targets proven-drained LDS regions.
template<int OUT_BF16>
__global__ __launch_bounds__(512) void k_gemm8ph(const unsigned short* __restrict__ A,
                                                 const unsigned short* __restrict__ B,
                                                 void* __restrict__ Cout,
                                                 int M, int N, int K, int nbx) {
  extern __shared__ __align__(16) char lds[];  // 2 x 65536 (A 32K + B 32K each)
  const int tid = threadIdx.x, lane = tid & 63, wid = tid >> 6;
  const int lr = lane & 15, lg = lane >> 4;
  const int wr = wid >> 2, wcn = wid & 3;

  // T1 bijective XCD swizzle (grid % 8 == 0: 192 / 128)
  const int nwg = gridDim.x, cpx = nwg >> 3;
  const int id = (int)blockIdx.x;
  const int sid = (id & 7) * cpx + (id >> 3);
  const int by = sid / nbx, bx = sid - by * nbx;

  const unsigned short* Ab = A + (size_t)by * 256 * K;
  const unsigned short* Bb = B + (size_t)bx * 256 * K;

  // stage source: thread covers tile-row (tid>>3) (+64 for 2nd load, +128 for half1),
  // 16B chunk (tid&7), source chunk pre-XORed with row&7 = (tid>>3)&7.
  const int cs = (((tid & 7) ^ ((tid >> 3) & 7)) << 3);  // shorts
  const unsigned short* pA = Ab + (size_t)(tid >> 3) * K + cs;
  const unsigned short* pB = Bb + (size_t)(tid >> 3) * K + cs;

  // read-side: row r at r*128 bytes; chunk XOR (lr&7)
  const int arb = (wr * 128 + lr) * 128;           // + (mh*4+m2)*2048 + chX
  const int brb = 32768 + (wcn * 64 + lr) * 128;   // + (nh*2+n2)*2048 + chX
  const int ch0 = (lg * 16) ^ ((lr & 7) << 4);
  const int ch1 = (64 + lg * 16) ^ ((lr & 7) << 4);

  f32x4 acc[8][4];
#pragma unroll
  for (int mi = 0; mi < 8; ++mi)
#pragma unroll
    for (int ni = 0; ni < 4; ++ni)
#pragma unroll
      for (int r = 0; r < 4; ++r) acc[mi][ni][r] = 0.f;

  // STG(px, xoff, t, h): stage half h (A rows h*128..h*128+127 or B ditto) of tile t
#define STG(px, xoff, t_, h_) do {                                                     \
    const unsigned short* s0_ = (px) + (size_t)(h_) * 128 * K + (size_t)(t_) * 64;     \
    char* d0_ = lds + (((t_) & 1) * 65536) + (xoff) + (h_) * 16384 + wid * 1024;       \
    __builtin_amdgcn_global_load_lds((gbl_u32*)s0_, (lds_u32*)d0_, 16, 0, 0);          \
    __builtin_amdgcn_global_load_lds((gbl_u32*)(s0_ + (size_t)64 * K),                 \
                                     (lds_u32*)(d0_ + 8192), 16, 0, 0);                \
  } while (0)

#define PH(mh, nh, READA, STAGEOP, LASTW) do {                                         \
    if (READA) {                                                                       \
      _Pragma("unroll") for (int m2 = 0; m2 < 4; ++m2) {                               \
        paf[m2][0] = *(const short8*)(bufp + arb + ((mh) * 4 + m2) * 2048 + ch0);      \
        paf[m2][1] = *(const short8*)(bufp + arb + ((mh) * 4 + m2) * 2048 + ch1);      \
      }                                                                                \
    }                                                                                  \
    _Pragma("unroll") for (int n2 = 0; n2 < 2; ++n2) {                                 \
      pbf[n2][0] = *(const short8*)(bufp + brb + ((nh) * 2 + n2) * 2048 + ch0);        \
      pbf[n2][1] = *(const short8*)(bufp + brb + ((nh) * 2 + n2) * 2048 + ch1);        \
    }                                                                                  \
    STAGEOP;                                                                           \
    __builtin_amdgcn_s_barrier();                                                      \
    asm volatile("s_waitcnt lgkmcnt(0)" ::: "memory");                                 \
    __builtin_amdgcn_s_setprio(1);                                                     \
    _Pragma("unroll") for (int m2 = 0; m2 < 4; ++m2)                                   \
      _Pragma("unroll") for (int n2 = 0; n2 < 2; ++n2) {                               \
        f32x4 a_ = acc[(mh) * 4 + m2][(nh) * 2 + n2];                                  \
        a_ = __builtin_amdgcn_mfma_f32_16x16x32_bf16(paf[m2][0], pbf[n2][0], a_, 0, 0, 0); \
        a_ = __builtin_amdgcn_mfma_f32_16x16x32_bf16(paf[m2][1], pbf[n2][1], a_, 0, 0, 0); \
        acc[(mh) * 4 + m2][(nh) * 2 + n2] = a_;                                        \
      }                                                                                \
    __builtin_amdgcn_s_setprio(0);                                                     \
    LASTW;                                                                             \
    __builtin_amdgcn_s_barrier();                                                      \
  } while (0)

  const int nt = K >> 6;
  // prologue: A0(0),B0(0),A1(0),B1(0),A0(1),B0(1) then retire tile0 (vmcnt 4)
  STG(pA, 0, 0, 0); STG(pB, 32768, 0, 0);
  STG(pA, 0, 0, 1); STG(pB, 32768, 0, 1);
  if (nt > 1) { STG(pA, 0, 1, 0); STG(pB, 32768, 1, 0); }
  asm volatile("s_waitcnt vmcnt(4)" ::: "memory");
  __builtin_amdgcn_s_barrier();

  for (int t = 0; t < nt; ++t) {
    const char* bufp = lds + (t & 1) * 65536;
    short8 paf[4][2], pbf[2][2];
    PH(0, 0, 1, { if (t + 1 < nt) STG(pA, 0, t + 1, 1); }, {});
    PH(0, 1, 0, { if (t + 1 < nt) STG(pB, 32768, t + 1, 1); }, {});
    PH(1, 0, 1, { if (t + 2 < nt) STG(pA, 0, t + 2, 0); }, {});
    PH(1, 1, 0, { if (t + 2 < nt) STG(pB, 32768, t + 2, 0); },
       { if (t + 2 < nt)      asm volatile("s_waitcnt vmcnt(4)" ::: "memory");
         else if (t + 1 < nt) asm volatile("s_waitcnt vmcnt(0)" ::: "memory"); });
  }

#undef STG
#undef PH

#pragma unroll
  for (int mi = 0; mi < 8; ++mi) {
    const int row0c = by * 256 + wr * 128 + mi * 16 + lg * 4;
#pragma unroll
    for (int ni = 0; ni < 4; ++ni) {
      const int col = bx * 256 + wcn * 64 + ni * 16 + lr;
#pragma unroll
      for (int r = 0; r < 4; ++r) {
        size_t idx = (size_t)(row0c + r) * N + col;
        if (OUT_BF16) ((unsigned short*)Cout)[idx] = f2bf(acc[mi][ni][r]);
        else          ((float*)Cout)[idx] = acc[mi][ni][r];
      }
    }
  }
}

// ---------------- RoPE + RMSNorm for Q and K heads ----------------
// Q scale folds 1/sqrt(128) * log2(e) so attention runs in exp2 domain.
__global__ __launch_bounds__(256) void k_rope_rms(const unsigned short* __restrict__ qkv,
                                                  const float* __restrict__ tbl,
                                                  unsigned short* __restrict__ Qo,
                                                  unsigned short* __restrict__ Ko) {
  const int lane = threadIdx.x & 63, wid = threadIdx.x >> 6;
  const int job = blockIdx.x * 4 + wid;
  const int row = job / 20;
  const int hh  = job - row * 20;
  const int b = row >> 11, t = row & (T_SEQ - 1);
  const unsigned short* src;
  unsigned short* dst;
  float scale;
  if (hh < NHQ) {
    src = qkv + (size_t)row * QKVN + hh * DHD;
    dst = Qo + (((size_t)b * NHQ + hh) * T_SEQ + t) * DHD;
    scale = 0.1275173019f;  // log2(e)/sqrt(128)
  } else {
    int h = hh - NHQ;
    src = qkv + (size_t)row * QKVN + CDIM + h * DHD;
    dst = Ko + (((size_t)b * NHKV + h) * T_SEQ + t) * DHD;
    scale = 1.f;
  }
  unsigned int pr = *reinterpret_cast<const unsigned int*>(src + lane * 2);
  float xe = bf2f(pr & 0xffffu), xo = bf2f(pr >> 16);
  float c = tbl[t * 64 + lane], s = tbl[T_SEQ * 64 + t * 64 + lane];
  float e = xe * c - xo * s;
  float o = xo * c + xe * s;
  float ss = e * e + o * o;
#pragma unroll
  for (int off = 1; off < 64; off <<= 1) ss += __shfl_xor(ss, off);
  float rn = rsqrtf(ss * (1.f / 128.f) + 1.1920929e-07f) * scale;
  unsigned short eb = f2bf(e * rn), ob = f2bf(o * rn);
  *reinterpret_cast<unsigned int*>(dst + lane * 2) = ((unsigned int)ob << 16) | eb;
}

// ---------------- V transpose ----------------
__global__ __launch_bounds__(256) void k_vtrans(const unsigned short* __restrict__ qkv,
                                                unsigned short* __restrict__ Vt) {
  __shared__ unsigned short tile[64][65];
  const int blk = blockIdx.x;
  const int dt = blk & 1;
  const int tt = (blk >> 1) & 31;
  const int h = (blk >> 6) & 3;
  const int b = blk >> 8;
  const int t0 = tt * 64, d0 = dt * 64;
#pragma unroll
  for (int i = 0; i < 16; ++i) {
    int idx = i * 256 + threadIdx.x;
    int tl = idx >> 6, dl = idx & 63;
    tile[tl][dl] = qkv[(size_t)(b * T_SEQ + t0 + tl) * QKVN + (CDIM + NHKV * DHD) + h * DHD + d0 + dl];
  }
  __syncthreads();
#pragma unroll
  for (int i = 0; i < 16; ++i) {
    int idx = i * 256 + threadIdx.x;
    int dl = idx >> 6, tl = idx & 63;
    Vt[((size_t)(b * NHKV + h) * DHD + d0 + dl) * T_SEQ + t0 + tl] = tile[tl][dl];
  }
}

// ---------------- windowed causal flash attention, LDS-staged K/V ----------------
__global__ __launch_bounds__(256) void k_attn(const unsigned short* __restrict__ Q,
                                              const unsigned short* __restrict__ K,
                                              const unsigned short* __restrict__ Vt,
                                              unsigned short* __restrict__ Y) {
  __shared__ __align__(16) char lds[49152];  // 3 slots x (K 8KB + V 8KB)
  const int tid = threadIdx.x, lane = tid & 63, wid = tid >> 6;
  const int l31 = lane & 31, hi = lane >> 5;

  const int id = (int)blockIdx.x;
  const int sid = (id & 7) * 64 + (id >> 3);
  const int qt = sid & 15;
  const int h = (sid >> 4) & 15;
  const int b = sid >> 8;
  const int hkv = h >> 2;
  const int q0 = qt * 128;
  const int q0g = q0 + wid * 32;

  const unsigned short* Qp = Q + (((size_t)b * NHQ + h) * T_SEQ + q0g) * DHD;
  const char* Kbyte = (const char*)(K + ((size_t)b * NHKV + hkv) * T_SEQ * DHD);
  const char* Vbyte = (const char*)(Vt + ((size_t)b * NHKV + hkv) * DHD * T_SEQ);

  const int ksrc0 = (tid >> 4) * 256 + (((tid & 15) * 16) ^ (((tid >> 4) & 7) << 4));
  const int vsrc0 = (tid >> 2) * 4096 + (((tid & 3) * 16) ^ (((tid >> 2) & 3) << 4));

  const int ksw = (l31 & 7) << 4;
  const int vsw = (l31 & 3) << 4;

#define STAGEKV(k0_, sb_) do {                                                           \
    const char* kt_ = Kbyte + (size_t)(k0_) * 256;                                       \
    const char* vt_ = Vbyte + (size_t)(k0_) * 2;                                         \
    __builtin_amdgcn_global_load_lds((gbl_u32*)(kt_ + ksrc0),                            \
        (lds_u32*)(lds + (sb_) + wid * 1024), 16, 0, 0);                                 \
    __builtin_amdgcn_global_load_lds((gbl_u32*)(kt_ + ksrc0 + 4096),                     \
        (lds_u32*)(lds + (sb_) + 4096 + wid * 1024), 16, 0, 0);                          \
    __builtin_amdgcn_global_load_lds((gbl_u32*)(vt_ + vsrc0),                            \
        (lds_u32*)(lds + (sb_) + 8192 + wid * 1024), 16, 0, 0);                          \
    __builtin_amdgcn_global_load_lds((gbl_u32*)(vt_ + vsrc0 + 262144),                   \
        (lds_u32*)(lds + (sb_) + 12288 + wid * 1024), 16, 0, 0);                         \
  } while (0)

  const int kt0 = (q0 >= SWIN) ? ((q0 - (SWIN - 1)) >> 5) : 0;
  const int kth = (q0 + 127) >> 5;

  STAGEKV(kt0 * 32, 0);

  short8 qf[8];
#pragma unroll
  for (int ds = 0; ds < 8; ++ds)
    qf[ds] = *reinterpret_cast<const short8*>(Qp + (size_t)l31 * DHD + ds * 16 + hi * 8);

  f32x16 accO[4];
#pragma unroll
  for (int dt = 0; dt < 4; ++dt)
#pragma unroll
    for (int r = 0; r < 16; ++r) accO[dt][r] = 0.f;
  float m = -1e30f, l = 0.f;
  const int qg = q0g + l31;

  int sl = 0;
  for (int t = kt0; t <= kth; ++t) {
    const int sln = (sl == 2) ? 0 : sl + 1;
    if (t < kth) {
      STAGEKV((t + 1) * 32, sln * 16384);
      asm volatile("s_waitcnt vmcnt(4)" ::: "memory");
    } else {
      asm volatile("s_waitcnt vmcnt(0)" ::: "memory");
    }
    __builtin_amdgcn_s_barrier();

    const int k0 = t * 32;
    if (k0 <= q0g && k0 + 31 >= q0g - (SWIN - 1)) {
      const char* kbase = lds + sl * 16384;
      const char* vbase = kbase + 8192;

      short8 kf[8];
#pragma unroll
      for (int ds = 0; ds < 8; ++ds)
        kf[ds] = *reinterpret_cast<const short8*>(kbase + l31 * 256 + ((ds * 32 + hi * 16) ^ ksw));

      f32x16 s;
#pragma unroll
      for (int r = 0; r < 16; ++r) s[r] = 0.f;
      __builtin_amdgcn_s_setprio(1);
#pragma unroll
      for (int ds = 0; ds < 8; ++ds)
        s = __builtin_amdgcn_mfma_f32_32x32x16_bf16(kf[ds], qf[ds], s, 0, 0, 0);
      __builtin_amdgcn_s_setprio(0);

      if (k0 < q0g - 480 || k0 >= q0g) {
#pragma unroll
        for (int r = 0; r < 16; ++r) {
          int kk = k0 + (r & 3) + 8 * (r >> 2) + 4 * hi;
          if (kk > qg || qg - kk >= SWIN) s[r] = -1e30f;
        }
      }

      float mx[8];
#pragma unroll
      for (int j = 0; j < 8; ++j) mx[j] = fmaxf(s[2 * j], s[2 * j + 1]);
      float a0 = fmaxf(mx[0], mx[1]), a1 = fmaxf(mx[2], mx[3]);
      float a2 = fmaxf(mx[4], mx[5]), a3 = fmaxf(mx[6], mx[7]);
      float tmax = fmaxf(fmaxf(a0, a1), fmaxf(a2, a3));
      tmax = fmaxf(tmax, __shfl_xor(tmax, 32));

      float mn = m;
      if (!__all(tmax <= m + 8.f)) {
        mn = fmaxf(m, tmax);
        float alpha = exp2_fast(m - mn);
        l *= alpha;
#pragma unroll
        for (int dt = 0; dt < 4; ++dt)
#pragma unroll
          for (int r = 0; r < 16; ++r) accO[dt][r] *= alpha;
        m = mn;
      }

#pragma unroll
      for (int r = 0; r < 16; ++r) s[r] = exp2_fast(s[r] - mn);
      float sx[8];
#pragma unroll
      for (int j = 0; j < 8; ++j) sx[j] = s[2 * j] + s[2 * j + 1];
      float b0 = sx[0] + sx[1], b1 = sx[2] + sx[3], b2 = sx[4] + sx[5], b3 = sx[6] + sx[7];
      float ps = (b0 + b1) + (b2 + b3);
      ps += __shfl_xor(ps, 32);
      l += ps;

      unsigned int w[8];
#pragma unroll
      for (int j = 0; j < 8; ++j)
        asm("v_cvt_pk_bf16_f32 %0, %1, %2" : "=v"(w[j]) : "v"(s[2 * j]), "v"(s[2 * j + 1]));
      asm("v_permlane32_swap_b32 %0, %1" : "+v"(w[0]), "+v"(w[2]));
      asm("v_permlane32_swap_b32 %0, %1" : "+v"(w[1]), "+v"(w[3]));
      asm("v_permlane32_swap_b32 %0, %1" : "+v"(w[4]), "+v"(w[6]));
      asm("v_permlane32_swap_b32 %0, %1" : "+v"(w[5]), "+v"(w[7]));
      u32x4 p0 = {w[0], w[1], w[2], w[3]};
      u32x4 p1 = {w[4], w[5], w[6], w[7]};
      short8 pf0 = __builtin_bit_cast(short8, p0);
      short8 pf1 = __builtin_bit_cast(short8, p1);

      __builtin_amdgcn_s_setprio(1);
#pragma unroll
      for (int dt = 0; dt < 4; ++dt) {
        const char* vrow = vbase + (dt * 2048 + l31 * 64);
        short8 vf0 = *reinterpret_cast<const short8*>(vrow + ((hi * 16) ^ vsw));
        short8 vf1 = *reinterpret_cast<const short8*>(vrow + ((32 + hi * 16) ^ vsw));
        accO[dt] = __builtin_amdgcn_mfma_f32_32x32x16_bf16(vf0, pf0, accO[dt], 0, 0, 0);
        accO[dt] = __builtin_amdgcn_mfma_f32_32x32x16_bf16(vf1, pf1, accO[dt], 0, 0, 0);
      }
      __builtin_amdgcn_s_setprio(0);
    }
    sl = sln;
  }
#undef STAGEKV

  __syncthreads();

  float inv = 1.f / l;
  char* obc = lds + wid * 8192;
#pragma unroll
  for (int dt = 0; dt < 4; ++dt)
#pragma unroll
    for (int j = 0; j < 8; ++j) {
      float a = accO[dt][2 * j] * inv, c = accO[dt][2 * j + 1] * inv;
      unsigned int wv;
      asm("v_cvt_pk_bf16_f32 %0, %1, %2" : "=v"(wv) : "v"(a), "v"(c));
      int d = dt * 32 + 2 * (j & 1) + 8 * (j >> 1) + 4 * hi;
      *reinterpret_cast<unsigned int*>(obc + l31 * 256 + ((d * 2) ^ ksw)) = wv;
    }
#pragma unroll
  for (int i = 0; i < 8; ++i) {
    int chunk = i * 64 + lane;
    int row = chunk >> 4, c8 = chunk & 15;
    short8 v = *reinterpret_cast<const short8*>(obc + row * 256 + ((c8 * 16) ^ ((row & 7) << 4)));
    *reinterpret_cast<short8*>(Y + ((size_t)b * T_SEQ + q0g + row) * CDIM + h * DHD + c8 * 8) = v;
  }
}

extern "C" void kernel_launch(void* const* d_in, const int* in_sizes, int n_in,
                              void* d_out, int out_size, void* d_ws, size_t ws_size,
                              hipStream_t stream) {
  const float* x     = (const float*)d_in[0];
  const float* wqkv  = (const float*)d_in[1];
  const float* wproj = (const float*)d_in[2];
  float* out = (float*)d_out;

  char* ws = (char*)d_ws;
  unsigned short* xb     = (unsigned short*)(ws + 0);         // 16 MB (reused as y)
  unsigned short* wqkvb  = (unsigned short*)(ws + 16777216);  // 12 MB
  unsigned short* wprojb = (unsigned short*)(ws + 29360128);  // 8 MB
  unsigned short* qkvb   = (unsigned short*)(ws + 37748736);  // 24 MB
  unsigned short* Qb     = (unsigned short*)(ws + 62914560);  // 16 MB
  unsigned short* Kb     = (unsigned short*)(ws + 79691776);  // 4 MB
  unsigned short* Vtb    = (unsigned short*)(ws + 83886080);  // 4 MB
  float* tbl             = (float*)(ws + 88080384);           // 1 MB
  unsigned short* yb     = xb;

  k_f2bf3<<<2048, 256, 0, stream>>>(x, xb, (NB * T_SEQ * CDIM) / 4,
                                    wqkv, wqkvb, (QKVN * CDIM) / 4,
                                    wproj, wprojb, (CDIM * CDIM) / 4);
  k_trig<<<(T_SEQ * 64 + 255) / 256, 256, 0, stream>>>(tbl);

  k_gemm8ph<1><<<(NB * T_SEQ / 256) * (QKVN / 256), 512, 131072, stream>>>(
      xb, wqkvb, qkvb, NB * T_SEQ, QKVN, CDIM, QKVN / 256);
  k_rope_rms<<<(NB * T_SEQ * (NHQ + NHKV)) / 4, 256, 0, stream>>>(qkvb, tbl, Qb, Kb);
  k_vtrans<<<NB * NHKV * 32 * 2, 256, 0, stream>>>(qkvb, Vtb);
  k_attn<<<NB * NHQ * (T_SEQ / 128), 256, 0, stream>>>(Qb, Kb, Vtb, yb);
  k_gemm8ph<0><<<(NB * T_SEQ / 256) * (CDIM / 256), 512, 131072, stream>>>(
      yb, wprojb, out, NB * T_SEQ, CDIM, CDIM, CDIM / 256);
}

// Round 12
// 167.168 us; speedup vs baseline: 1.2201x; 1.2201x over previous
//
#include <hip/hip_runtime.h>
#include <stdint.h>

#define T_SEQ 2048
#define NB    2
#define DHD   128
#define NHQ   16
#define NHKV  4
#define SWIN  512
#define CDIM  2048
#define QKVN  3072
#define GBK   32

typedef __attribute__((ext_vector_type(8))) short short8;
typedef __attribute__((ext_vector_type(4))) float f32x4;
typedef __attribute__((ext_vector_type(16))) float f32x16;
typedef __attribute__((ext_vector_type(4))) unsigned int u32x4;
typedef __attribute__((address_space(3))) unsigned int lds_u32;
typedef __attribute__((address_space(1))) const unsigned int gbl_u32;

__device__ __forceinline__ unsigned short f2bf(float f) {
  unsigned int u = __float_as_uint(f);
  u += 0x7fffu + ((u >> 16) & 1u);
  return (unsigned short)(u >> 16);
}
__device__ __forceinline__ float bf2f(unsigned int h) {
  return __uint_as_float(h << 16);
}
__device__ __forceinline__ float exp2_fast(float x) {
  float r;
  asm("v_exp_f32 %0, %1" : "=v"(r) : "v"(x));
  return r;
}

// ---------------- fp32 -> bf16 for all three inputs, one launch ----------------
__global__ __launch_bounds__(256) void k_f2bf3(const float* __restrict__ a, unsigned short* __restrict__ oa, int na4,
                                               const float* __restrict__ b, unsigned short* __restrict__ ob, int nb4,
                                               const float* __restrict__ c, unsigned short* __restrict__ oc, int nc4) {
  const int n = na4 + nb4 + nc4;
  for (int i = blockIdx.x * 256 + threadIdx.x; i < n; i += gridDim.x * 256) {
    const float* src; unsigned short* dst; int j = i;
    if (j < na4) { src = a; dst = oa; }
    else if (j < na4 + nb4) { j -= na4; src = b; dst = ob; }
    else { j -= na4 + nb4; src = c; dst = oc; }
    float4 v = reinterpret_cast<const float4*>(src)[j];
    uint2 o;
    o.x = ((unsigned int)f2bf(v.y) << 16) | f2bf(v.x);
    o.y = ((unsigned int)f2bf(v.w) << 16) | f2bf(v.z);
    reinterpret_cast<uint2*>(dst)[j] = o;
  }
}

// ---------------- RoPE trig table ----------------
__global__ __launch_bounds__(256) void k_trig(float* __restrict__ tbl) {
  int i = blockIdx.x * 256 + threadIdx.x;
  if (i >= T_SEQ * 64) return;
  int t = i >> 6, f = i & 63;
  float invf = powf(10000.f, -(float)f * (1.f / 64.f));
  float ang = (float)t * invf;
  tbl[i] = cosf(ang);
  tbl[T_SEQ * 64 + i] = sinf(ang);
}

// ---------------- 256x192 ring-4 GEMM (QKV): full 256-block fill ----------------
// R10 measured-best: 59.3 us, MfmaUtil 35%, 0 bank conflicts.
template<int OUT_BF16>
__global__ __launch_bounds__(512, 2) void k_gemm192(const unsigned short* __restrict__ A,
                                                    const unsigned short* __restrict__ B,
                                                    void* __restrict__ Cout,
                                                    int M, int N, int K, int nbx) {
  extern __shared__ __align__(16) char lds[];  // 4 slots x (A 16KB + B 12KB) = 112 KiB
  const int tid = threadIdx.x, lane = tid & 63, wid = tid >> 6;
  const int lr = lane & 15, lg = lane >> 4;
  const int wr = wid >> 2, wcn = wid & 3;

  const int nwg = gridDim.x, cpx = nwg >> 3;
  const int id = (int)blockIdx.x;
  const int sid = (id & 7) * cpx + (id >> 3);
  const int by = sid / nbx, bx = sid - by * nbx;

  const unsigned short* Ab = A + (size_t)by * 256 * K;
  const unsigned short* Bb = B + (size_t)bx * 192 * K;

  const int row0 = tid >> 2;
  const int blk  = tid & 3;
  const int col0 = ((blk * 16) ^ (((row0 >> 1) & 3) << 4)) >> 1;
  const unsigned short* pA0 = Ab + (size_t)row0 * K + col0;
  const unsigned short* pA1 = pA0 + (size_t)128 * K;
  const unsigned short* pB0 = Bb + (size_t)row0 * K + col0;
  const unsigned short* pB2 = pB0 + (size_t)128 * K;

  const int sw  = ((lg ^ ((lr >> 1) & 3)) << 4);
  const int arb = (wr * 128 + lr) * 64 + sw;
  const int brb = 16384 + (wcn * 48 + lr) * 64 + sw;

  f32x4 acc[8][3];
#pragma unroll
  for (int mi = 0; mi < 8; ++mi)
#pragma unroll
    for (int ni = 0; ni < 3; ++ni)
#pragma unroll
      for (int r = 0; r < 4; ++r) acc[mi][ni][r] = 0.f;

#define STAGE(t) do {                                                                  \
    const int sl_ = (t) & 3; const int ko_ = (t) * GBK;                                \
    char* sb_ = lds + sl_ * 28672;                                                     \
    __builtin_amdgcn_global_load_lds((gbl_u32*)(pA0 + ko_),                            \
        (lds_u32*)(sb_ + wid * 1024), 16, 0, 0);                                       \
    __builtin_amdgcn_global_load_lds((gbl_u32*)(pA1 + ko_),                            \
        (lds_u32*)(sb_ + 8192 + wid * 1024), 16, 0, 0);                                \
    __builtin_amdgcn_global_load_lds((gbl_u32*)(pB0 + ko_),                            \
        (lds_u32*)(sb_ + 16384 + wid * 1024), 16, 0, 0);                               \
    if (wid < 4)                                                                       \
      __builtin_amdgcn_global_load_lds((gbl_u32*)(pB2 + ko_),                          \
          (lds_u32*)(sb_ + 24576 + wid * 1024), 16, 0, 0);                             \
  } while (0)

#define COMPUTE(t) do {                                                                \
    const int sl_ = (t) & 3;                                                           \
    const char* sb_ = lds + sl_ * 28672;                                               \
    short8 afr[8], bfr[3];                                                             \
    _Pragma("unroll") for (int mi = 0; mi < 8; ++mi)                                   \
      afr[mi] = *reinterpret_cast<const short8*>(sb_ + arb + mi * 1024);               \
    _Pragma("unroll") for (int ni = 0; ni < 3; ++ni)                                   \
      bfr[ni] = *reinterpret_cast<const short8*>(sb_ + brb + ni * 1024);               \
    __builtin_amdgcn_s_setprio(1);                                                     \
    _Pragma("unroll") for (int mi = 0; mi < 8; ++mi)                                   \
      _Pragma("unroll") for (int ni = 0; ni < 3; ++ni)                                 \
        acc[mi][ni] = __builtin_amdgcn_mfma_f32_16x16x32_bf16(afr[mi], bfr[ni],        \
                                                              acc[mi][ni], 0, 0, 0);   \
    __builtin_amdgcn_s_setprio(0);                                                     \
  } while (0)

#define WAITBAR2(nlo, nhi) do {                                                        \
    if (wid < 4) asm volatile("s_waitcnt vmcnt(" #nlo ")" ::: "memory");               \
    else         asm volatile("s_waitcnt vmcnt(" #nhi ")" ::: "memory");               \
    __builtin_amdgcn_s_barrier();                                                      \
    asm volatile("" ::: "memory");                                                     \
  } while (0)

  const int nt = K / GBK;
  STAGE(0); STAGE(1); STAGE(2);
  for (int t = 0; t < nt - 3; ++t) {
    WAITBAR2(10, 8);
    STAGE(t + 3);
    COMPUTE(t);
  }
  WAITBAR2(10, 8); COMPUTE(nt - 3);
  WAITBAR2(5, 4);  COMPUTE(nt - 2);
  WAITBAR2(0, 0);  COMPUTE(nt - 1);

#undef STAGE
#undef COMPUTE
#undef WAITBAR2

#pragma unroll
  for (int mi = 0; mi < 8; ++mi) {
    const int row0c = by * 256 + wr * 128 + mi * 16 + lg * 4;
#pragma unroll
    for (int ni = 0; ni < 3; ++ni) {
      const int col = bx * 192 + wcn * 48 + ni * 16 + lr;
#pragma unroll
      for (int r = 0; r < 4; ++r) {
        size_t idx = (size_t)(row0c + r) * N + col;
        if (OUT_BF16) ((unsigned short*)Cout)[idx] = f2bf(acc[mi][ni][r]);
        else          ((float*)Cout)[idx] = acc[mi][ni][r];
      }
    }
  }
}

// ---------------- 128x256 ring-3 GEMM (proj): full 256-block fill ----------------
template<int OUT_BF16>
__global__ __launch_bounds__(512) void k_gemm128(const unsigned short* __restrict__ A,
                                                 const unsigned short* __restrict__ B,
                                                 void* __restrict__ Cout,
                                                 int M, int N, int K, int nbx) {
  extern __shared__ __align__(16) char lds[];  // 3 slots x (A 8KB + B 16KB) = 72 KiB
  const int tid = threadIdx.x, lane = tid & 63, wid = tid >> 6;
  const int lr = lane & 15, lg = lane >> 4;
  const int wr = wid >> 2, wcn = wid & 3;

  const int nwg = gridDim.x, cpx = nwg >> 3;
  const int id = (int)blockIdx.x;
  const int sid = (id & 7) * cpx + (id >> 3);
  const int by = sid / nbx, bx = sid - by * nbx;

  const unsigned short* Ab = A + (size_t)by * 128 * K;
  const unsigned short* Bb = B + (size_t)bx * 256 * K;

  const int row0 = tid >> 2;
  const int blk  = tid & 3;
  const int col0 = ((blk * 16) ^ (((row0 >> 1) & 3) << 4)) >> 1;
  const unsigned short* pA0 = Ab + (size_t)row0 * K + col0;
  const unsigned short* pB0 = Bb + (size_t)row0 * K + col0;
  const unsigned short* pB1 = pB0 + (size_t)128 * K;

  const int sw  = ((lg ^ ((lr >> 1) & 3)) << 4);
  const int arb = (wr * 64 + lr) * 64 + sw;
  const int brb = (wcn * 64 + lr) * 64 + sw;

  f32x4 acc[4][4];
#pragma unroll
  for (int mi = 0; mi < 4; ++mi)
#pragma unroll
    for (int ni = 0; ni < 4; ++ni)
#pragma unroll
      for (int r = 0; r < 4; ++r) acc[mi][ni][r] = 0.f;

#define STAGE(t, sl_) do {                                                             \
    const int ko_ = (t) * GBK;                                                         \
    __builtin_amdgcn_global_load_lds((gbl_u32*)(pA0 + ko_),                            \
        (lds_u32*)(lds + (sl_) * 24576 + wid * 1024), 16, 0, 0);                       \
    __builtin_amdgcn_global_load_lds((gbl_u32*)(pB0 + ko_),                            \
        (lds_u32*)(lds + (sl_) * 24576 + 8192 + wid * 1024), 16, 0, 0);                \
    __builtin_amdgcn_global_load_lds((gbl_u32*)(pB1 + ko_),                            \
        (lds_u32*)(lds + (sl_) * 24576 + 16384 + wid * 1024), 16, 0, 0);               \
  } while (0)

#define COMPUTE(sl_) do {                                                              \
    const char* As_ = lds + (sl_) * 24576;                                             \
    const char* Bs_ = As_ + 8192;                                                      \
    short8 afr[4], bfr[4];                                                             \
    _Pragma("unroll") for (int mi = 0; mi < 4; ++mi)                                   \
      afr[mi] = *reinterpret_cast<const short8*>(As_ + arb + mi * 1024);               \
    _Pragma("unroll") for (int ni = 0; ni < 4; ++ni)                                   \
      bfr[ni] = *reinterpret_cast<const short8*>(Bs_ + brb + ni * 1024);               \
    __builtin_amdgcn_s_setprio(1);                                                     \
    _Pragma("unroll") for (int mi = 0; mi < 4; ++mi)                                   \
      _Pragma("unroll") for (int ni = 0; ni < 4; ++ni)                                 \
        acc[mi][ni] = __builtin_amdgcn_mfma_f32_16x16x32_bf16(afr[mi], bfr[ni],        \
                                                              acc[mi][ni], 0, 0, 0);   \
    __builtin_amdgcn_s_setprio(0);                                                     \
  } while (0)

#define WAITBAR(n) do {                                                                \
    asm volatile("s_waitcnt vmcnt(" #n ")" ::: "memory");                              \
    __builtin_amdgcn_s_barrier();                                                      \
    asm volatile("" ::: "memory");                                                     \
  } while (0)

  const int nt = K / GBK;
  STAGE(0, 0); STAGE(1, 1);
  int sc = 0, ss = 2;
  for (int t = 0; t < nt - 2; ++t) {
    WAITBAR(3);
    STAGE(t + 2, ss);
    COMPUTE(sc);
    sc = (sc == 2) ? 0 : sc + 1;
    ss = (ss == 2) ? 0 : ss + 1;
  }
  WAITBAR(3);
  COMPUTE(sc);
  sc = (sc == 2) ? 0 : sc + 1;
  WAITBAR(0);
  COMPUTE(sc);

#undef STAGE
#undef COMPUTE
#undef WAITBAR

#pragma unroll
  for (int mi = 0; mi < 4; ++mi) {
    const int row0c = by * 128 + wr * 64 + mi * 16 + lg * 4;
#pragma unroll
    for (int ni = 0; ni < 4; ++ni) {
      const int col = bx * 256 + wcn * 64 + ni * 16 + lr;
#pragma unroll
      for (int r = 0; r < 4; ++r) {
        size_t idx = (size_t)(row0c + r) * N + col;
        if (OUT_BF16) ((unsigned short*)Cout)[idx] = f2bf(acc[mi][ni][r]);
        else          ((float*)Cout)[idx] = acc[mi][ni][r];
      }
    }
  }
}

// ---------------- RoPE + RMSNorm for Q and K heads ----------------
__global__ __launch_bounds__(256) void k_rope_rms(const unsigned short* __restrict__ qkv,
                                                  const float* __restrict__ tbl,
                                                  unsigned short* __restrict__ Qo,
                                                  unsigned short* __restrict__ Ko) {
  const int lane = threadIdx.x & 63, wid = threadIdx.x >> 6;
  const int job = blockIdx.x * 4 + wid;
  const int row = job / 20;
  const int hh  = job - row * 20;
  const int b = row >> 11, t = row & (T_SEQ - 1);
  const unsigned short* src;
  unsigned short* dst;
  float scale;
  if (hh < NHQ) {
    src = qkv + (size_t)row * QKVN + hh * DHD;
    dst = Qo + (((size_t)b * NHQ + hh) * T_SEQ + t) * DHD;
    scale = 0.1275173019f;  // log2(e)/sqrt(128)
  } else {
    int h = hh - NHQ;
    src = qkv + (size_t)row * QKVN + CDIM + h * DHD;
    dst = Ko + (((size_t)b * NHKV + h) * T_SEQ + t) * DHD;
    scale = 1.f;
  }
  unsigned int pr = *reinterpret_cast<const unsigned int*>(src + lane * 2);
  float xe = bf2f(pr & 0xffffu), xo = bf2f(pr >> 16);
  float c = tbl[t * 64 + lane], s = tbl[T_SEQ * 64 + t * 64 + lane];
  float e = xe * c - xo * s;
  float o = xo * c + xe * s;
  float ss = e * e + o * o;
#pragma unroll
  for (int off = 1; off < 64; off <<= 1) ss += __shfl_xor(ss, off);
  float rn = rsqrtf(ss * (1.f / 128.f) + 1.1920929e-07f) * scale;
  unsigned short eb = f2bf(e * rn), ob = f2bf(o * rn);
  *reinterpret_cast<unsigned int*>(dst + lane * 2) = ((unsigned int)ob << 16) | eb;
}

// ---------------- V transpose ----------------
__global__ __launch_bounds__(256) void k_vtrans(const unsigned short* __restrict__ qkv,
                                                unsigned short* __restrict__ Vt) {
  __shared__ unsigned short tile[64][65];
  const int blk = blockIdx.x;
  const int dt = blk & 1;
  const int tt = (blk >> 1) & 31;
  const int h = (blk >> 6) & 3;
  const int b = blk >> 8;
  const int t0 = tt * 64, d0 = dt * 64;
#pragma unroll
  for (int i = 0; i < 16; ++i) {
    int idx = i * 256 + threadIdx.x;
    int tl = idx >> 6, dl = idx & 63;
    tile[tl][dl] = qkv[(size_t)(b * T_SEQ + t0 + tl) * QKVN + (CDIM + NHKV * DHD) + h * DHD + d0 + dl];
  }
  __syncthreads();
#pragma unroll
  for (int i = 0; i < 16; ++i) {
    int idx = i * 256 + threadIdx.x;
    int dl = idx >> 6, tl = idx & 63;
    Vt[((size_t)(b * NHKV + h) * DHD + d0 + dl) * T_SEQ + t0 + tl] = tile[tl][dl];
  }
}

// ---------------- windowed causal flash attention, LDS-staged K/V ----------------
// block = (b, h, 256-q tile), 8 waves x 32 q-rows (512 thr). K/V tiles (32 keys)
// staged once per block into a 3-slot LDS ring (2 gload_lds/tile), vmcnt(2),
// one barrier/tile. Swapped 32x32 MFMA, lane-local softmax (exp2 domain).
__global__ __launch_bounds__(512) void k_attn(const unsigned short* __restrict__ Q,
                                              const unsigned short* __restrict__ K,
                                              const unsigned short* __restrict__ Vt,
                                              unsigned short* __restrict__ Y) {
  __shared__ __align__(16) char lds[65536];  // 3 x 16KB staging ring; 64KB epilogue
  const int tid = threadIdx.x, lane = tid & 63, wid = tid >> 6;
  const int l31 = lane & 31, hi = lane >> 5;

  // XCD swizzle over 256 blocks
  const int id = (int)blockIdx.x;
  const int sid = (id & 7) * 32 + (id >> 3);
  const int qt = sid & 7;
  const int h = (sid >> 3) & 15;
  const int b = sid >> 7;
  const int hkv = h >> 2;
  const int q0 = qt * 256;
  const int q0g = q0 + wid * 32;

  const unsigned short* Qp = Q + (((size_t)b * NHQ + h) * T_SEQ + q0g) * DHD;
  const char* Kbyte = (const char*)(K + ((size_t)b * NHKV + hkv) * T_SEQ * DHD);
  const char* Vbyte = (const char*)(Vt + ((size_t)b * NHKV + hkv) * DHD * T_SEQ);

  // staging source offsets (512 threads, chunk = tid)
  const int ksrc = (tid >> 4) * 256 + (((tid & 15) * 16) ^ (((tid >> 4) & 7) << 4));
  const int vsrc = (tid >> 2) * 4096 + (((tid & 3) * 16) ^ (((tid >> 2) & 3) << 4));

  const int ksw = (l31 & 7) << 4;
  const int vsw = (l31 & 3) << 4;

#define STAGEKV(k0_, sb_) do {                                                           \
    const char* kt_ = Kbyte + (size_t)(k0_) * 256;                                       \
    const char* vt_ = Vbyte + (size_t)(k0_) * 2;                                         \
    __builtin_amdgcn_global_load_lds((gbl_u32*)(kt_ + ksrc),                             \
        (lds_u32*)(lds + (sb_) + wid * 1024), 16, 0, 0);                                 \
    __builtin_amdgcn_global_load_lds((gbl_u32*)(vt_ + vsrc),                             \
        (lds_u32*)(lds + (sb_) + 8192 + wid * 1024), 16, 0, 0);                          \
  } while (0)

  const int kt0 = (q0 >= SWIN) ? ((q0 - (SWIN - 1)) >> 5) : 0;
  const int kth = (q0 + 255) >> 5;

  STAGEKV(kt0 * 32, 0);

  short8 qf[8];
#pragma unroll
  for (int ds = 0; ds < 8; ++ds)
    qf[ds] = *reinterpret_cast<const short8*>(Qp + (size_t)l31 * DHD + ds * 16 + hi * 8);

  f32x16 accO[4];
#pragma unroll
  for (int dt = 0; dt < 4; ++dt)
#pragma unroll
    for (int r = 0; r < 16; ++r) accO[dt][r] = 0.f;
  float m = -1e30f, l = 0.f;
  const int qg = q0g + l31;

  int sl = 0;
  for (int t = kt0; t <= kth; ++t) {
    const int sln = (sl == 2) ? 0 : sl + 1;
    if (t < kth) {
      STAGEKV((t + 1) * 32, sln * 16384);
      asm volatile("s_waitcnt vmcnt(2)" ::: "memory");
    } else {
      asm volatile("s_waitcnt vmcnt(0)" ::: "memory");
    }
    __builtin_amdgcn_s_barrier();

    const int k0 = t * 32;
    if (k0 <= q0g && k0 + 31 >= q0g - (SWIN - 1)) {
      const char* kbase = lds + sl * 16384;
      const char* vbase = kbase + 8192;

      short8 kf[8];
#pragma unroll
      for (int ds = 0; ds < 8; ++ds)
        kf[ds] = *reinterpret_cast<const short8*>(kbase + l31 * 256 + ((ds * 32 + hi * 16) ^ ksw));

      f32x16 s;
#pragma unroll
      for (int r = 0; r < 16; ++r) s[r] = 0.f;
      __builtin_amdgcn_s_setprio(1);
#pragma unroll
      for (int ds = 0; ds < 8; ++ds)
        s = __builtin_amdgcn_mfma_f32_32x32x16_bf16(kf[ds], qf[ds], s, 0, 0, 0);
      __builtin_amdgcn_s_setprio(0);

      if (k0 < q0g - 480 || k0 >= q0g) {
#pragma unroll
        for (int r = 0; r < 16; ++r) {
          int kk = k0 + (r & 3) + 8 * (r >> 2) + 4 * hi;
          if (kk > qg || qg - kk >= SWIN) s[r] = -1e30f;
        }
      }

      float mx[8];
#pragma unroll
      for (int j = 0; j < 8; ++j) mx[j] = fmaxf(s[2 * j], s[2 * j + 1]);
      float a0 = fmaxf(mx[0], mx[1]), a1 = fmaxf(mx[2], mx[3]);
      float a2 = fmaxf(mx[4], mx[5]), a3 = fmaxf(mx[6], mx[7]);
      float tmax = fmaxf(fmaxf(a0, a1), fmaxf(a2, a3));
      tmax = fmaxf(tmax, __shfl_xor(tmax, 32));

      float mn = m;
      if (!__all(tmax <= m + 8.f)) {
        mn = fmaxf(m, tmax);
        float alpha = exp2_fast(m - mn);
        l *= alpha;
#pragma unroll
        for (int dt = 0; dt < 4; ++dt)
#pragma unroll
          for (int r = 0; r < 16; ++r) accO[dt][r] *= alpha;
        m = mn;
      }

#pragma unroll
      for (int r = 0; r < 16; ++r) s[r] = exp2_fast(s[r] - mn);
      float sx[8];
#pragma unroll
      for (int j = 0; j < 8; ++j) sx[j] = s[2 * j] + s[2 * j + 1];
      float b0 = sx[0] + sx[1], b1 = sx[2] + sx[3], b2 = sx[4] + sx[5], b3 = sx[6] + sx[7];
      float ps = (b0 + b1) + (b2 + b3);
      ps += __shfl_xor(ps, 32);
      l += ps;

      unsigned int w[8];
#pragma unroll
      for (int j = 0; j < 8; ++j)
        asm("v_cvt_pk_bf16_f32 %0, %1, %2" : "=v"(w[j]) : "v"(s[2 * j]), "v"(s[2 * j + 1]));
      asm("v_permlane32_swap_b32 %0, %1" : "+v"(w[0]), "+v"(w[2]));
      asm("v_permlane32_swap_b32 %0, %1" : "+v"(w[1]), "+v"(w[3]));
      asm("v_permlane32_swap_b32 %0, %1" : "+v"(w[4]), "+v"(w[6]));
      asm("v_permlane32_swap_b32 %0, %1" : "+v"(w[5]), "+v"(w[7]));
      u32x4 p0 = {w[0], w[1], w[2], w[3]};
      u32x4 p1 = {w[4], w[5], w[6], w[7]};
      short8 pf0 = __builtin_bit_cast(short8, p0);
      short8 pf1 = __builtin_bit_cast(short8, p1);

      __builtin_amdgcn_s_setprio(1);
#pragma unroll
      for (int dt = 0; dt < 4; ++dt) {
        const char* vrow = vbase + (dt * 2048 + l31 * 64);
        short8 vf0 = *reinterpret_cast<const short8*>(vrow + ((hi * 16) ^ vsw));
        short8 vf1 = *reinterpret_cast<const short8*>(vrow + ((32 + hi * 16) ^ vsw));
        accO[dt] = __builtin_amdgcn_mfma_f32_32x32x16_bf16(vf0, pf0, accO[dt], 0, 0, 0);
        accO[dt] = __builtin_amdgcn_mfma_f32_32x32x16_bf16(vf1, pf1, accO[dt], 0, 0, 0);
      }
      __builtin_amdgcn_s_setprio(0);
    }
    sl = sln;
  }
#undef STAGEKV

  __syncthreads();  // staging done; reuse full 64KB for epilogue

  float inv = 1.f / l;
  char* obc = lds + wid * 8192;  // 8 waves x 8KB
#pragma unroll
  for (int dt = 0; dt < 4; ++dt)
#pragma unroll
    for (int j = 0; j < 8; ++j) {
      float a = accO[dt][2 * j] * inv, c = accO[dt][2 * j + 1] * inv;
      unsigned int wv;
      asm("v_cvt_pk_bf16_f32 %0, %1, %2" : "=v"(wv) : "v"(a), "v"(c));
      int d = dt * 32 + 2 * (j & 1) + 8 * (j >> 1) + 4 * hi;
      *reinterpret_cast<unsigned int*>(obc + l31 * 256 + ((d * 2) ^ ksw)) = wv;
    }
#pragma unroll
  for (int i = 0; i < 8; ++i) {
    int chunk = i * 64 + lane;
    int row = chunk >> 4, c8 = chunk & 15;
    short8 v = *reinterpret_cast<const short8*>(obc + row * 256 + ((c8 * 16) ^ ((row & 7) << 4)));
    *reinterpret_cast<short8*>(Y + ((size_t)b * T_SEQ + q0g + row) * CDIM + h * DHD + c8 * 8) = v;
  }
}

extern "C" void kernel_launch(void* const* d_in, const int* in_sizes, int n_in,
                              void* d_out, int out_size, void* d_ws, size_t ws_size,
                              hipStream_t stream) {
  const float* x     = (const float*)d_in[0];
  const float* wqkv  = (const float*)d_in[1];
  const float* wproj = (const float*)d_in[2];
  float* out = (float*)d_out;

  char* ws = (char*)d_ws;
  unsigned short* xb     = (unsigned short*)(ws + 0);         // 16 MB (reused as y)
  unsigned short* wqkvb  = (unsigned short*)(ws + 16777216);  // 12 MB
  unsigned short* wprojb = (unsigned short*)(ws + 29360128);  // 8 MB
  unsigned short* qkvb   = (unsigned short*)(ws + 37748736);  // 24 MB
  unsigned short* Qb     = (unsigned short*)(ws + 62914560);  // 16 MB
  unsigned short* Kb     = (unsigned short*)(ws + 79691776);  // 4 MB
  unsigned short* Vtb    = (unsigned short*)(ws + 83886080);  // 4 MB
  float* tbl             = (float*)(ws + 88080384);           // 1 MB
  unsigned short* yb     = xb;

  k_f2bf3<<<2048, 256, 0, stream>>>(x, xb, (NB * T_SEQ * CDIM) / 4,
                                    wqkv, wqkvb, (QKVN * CDIM) / 4,
                                    wproj, wprojb, (CDIM * CDIM) / 4);
  k_trig<<<(T_SEQ * 64 + 255) / 256, 256, 0, stream>>>(tbl);

  // QKV: 256x192 tile -> 256 blocks (exact CU fill)
  k_gemm192<1><<<256, 512, 114688, stream>>>(
      xb, wqkvb, qkvb, NB * T_SEQ, QKVN, CDIM, QKVN / 192);
  k_rope_rms<<<(NB * T_SEQ * (NHQ + NHKV)) / 4, 256, 0, stream>>>(qkvb, tbl, Qb, Kb);
  k_vtrans<<<NB * NHKV * 32 * 2, 256, 0, stream>>>(qkvb, Vtb);
  // attn: 256-q tiles, 8 waves -> 256 blocks
  k_attn<<<NB * NHQ * (T_SEQ / 256), 512, 0, stream>>>(Qb, Kb, Vtb, yb);
  // proj: 128x256 tile -> 256 blocks (exact CU fill)
  k_gemm128<0><<<256, 512, 73728, stream>>>(
      yb, wprojb, out, NB * T_SEQ, CDIM, CDIM, CDIM / 256);
}

// Round 13
// 161.062 us; speedup vs baseline: 1.2663x; 1.0379x over previous
//
#include <hip/hip_runtime.h>
#include <stdint.h>

#define T_SEQ 2048
#define NB    2
#define DHD   128
#define NHQ   16
#define NHKV  4
#define SWIN  512
#define CDIM  2048
#define QKVN  3072
#define GBK   32

typedef __attribute__((ext_vector_type(8))) short short8;
typedef __attribute__((ext_vector_type(4))) float f32x4;
typedef __attribute__((ext_vector_type(16))) float f32x16;
typedef __attribute__((ext_vector_type(4))) unsigned int u32x4;
typedef __attribute__((address_space(3))) unsigned int lds_u32;
typedef __attribute__((address_space(1))) const unsigned int gbl_u32;

__device__ __forceinline__ unsigned short f2bf(float f) {
  unsigned int u = __float_as_uint(f);
  u += 0x7fffu + ((u >> 16) & 1u);
  return (unsigned short)(u >> 16);
}
__device__ __forceinline__ float bf2f(unsigned int h) {
  return __uint_as_float(h << 16);
}
__device__ __forceinline__ float exp2_fast(float x) {
  float r;
  asm("v_exp_f32 %0, %1" : "=v"(r) : "v"(x));
  return r;
}

// ---------------- fp32 -> bf16 (x, wqkv, wproj) + RoPE trig table, one launch ----
__global__ __launch_bounds__(256) void k_f2bf3t(const float* __restrict__ a, unsigned short* __restrict__ oa, int na4,
                                                const float* __restrict__ b, unsigned short* __restrict__ ob, int nb4,
                                                const float* __restrict__ c, unsigned short* __restrict__ oc, int nc4,
                                                float* __restrict__ tbl) {
  // trig: first 512 blocks write one element each (hides under memory-bound convert)
  if (blockIdx.x < 512) {
    int i = blockIdx.x * 256 + threadIdx.x;
    int t = i >> 6, f = i & 63;
    float invf = powf(10000.f, -(float)f * (1.f / 64.f));
    float ang = (float)t * invf;
    tbl[i] = cosf(ang);
    tbl[T_SEQ * 64 + i] = sinf(ang);
  }
  const int n = na4 + nb4 + nc4;
  for (int i = blockIdx.x * 256 + threadIdx.x; i < n; i += gridDim.x * 256) {
    const float* src; unsigned short* dst; int j = i;
    if (j < na4) { src = a; dst = oa; }
    else if (j < na4 + nb4) { j -= na4; src = b; dst = ob; }
    else { j -= na4 + nb4; src = c; dst = oc; }
    float4 v = reinterpret_cast<const float4*>(src)[j];
    uint2 o;
    o.x = ((unsigned int)f2bf(v.y) << 16) | f2bf(v.x);
    o.y = ((unsigned int)f2bf(v.w) << 16) | f2bf(v.z);
    reinterpret_cast<uint2*>(dst)[j] = o;
  }
}

// ---------------- 256x192 ring-4 GEMM (QKV): full 256-block fill ----------------
// R10 measured-best: 59.3 us, MfmaUtil 35%, 0 bank conflicts. DO NOT TOUCH.
template<int OUT_BF16>
__global__ __launch_bounds__(512, 2) void k_gemm192(const unsigned short* __restrict__ A,
                                                    const unsigned short* __restrict__ B,
                                                    void* __restrict__ Cout,
                                                    int M, int N, int K, int nbx) {
  extern __shared__ __align__(16) char lds[];  // 4 slots x (A 16KB + B 12KB) = 112 KiB
  const int tid = threadIdx.x, lane = tid & 63, wid = tid >> 6;
  const int lr = lane & 15, lg = lane >> 4;
  const int wr = wid >> 2, wcn = wid & 3;

  const int nwg = gridDim.x, cpx = nwg >> 3;
  const int id = (int)blockIdx.x;
  const int sid = (id & 7) * cpx + (id >> 3);
  const int by = sid / nbx, bx = sid - by * nbx;

  const unsigned short* Ab = A + (size_t)by * 256 * K;
  const unsigned short* Bb = B + (size_t)bx * 192 * K;

  const int row0 = tid >> 2;
  const int blk  = tid & 3;
  const int col0 = ((blk * 16) ^ (((row0 >> 1) & 3) << 4)) >> 1;
  const unsigned short* pA0 = Ab + (size_t)row0 * K + col0;
  const unsigned short* pA1 = pA0 + (size_t)128 * K;
  const unsigned short* pB0 = Bb + (size_t)row0 * K + col0;
  const unsigned short* pB2 = pB0 + (size_t)128 * K;

  const int sw  = ((lg ^ ((lr >> 1) & 3)) << 4);
  const int arb = (wr * 128 + lr) * 64 + sw;
  const int brb = 16384 + (wcn * 48 + lr) * 64 + sw;

  f32x4 acc[8][3];
#pragma unroll
  for (int mi = 0; mi < 8; ++mi)
#pragma unroll
    for (int ni = 0; ni < 3; ++ni)
#pragma unroll
      for (int r = 0; r < 4; ++r) acc[mi][ni][r] = 0.f;

#define STAGE(t) do {                                                                  \
    const int sl_ = (t) & 3; const int ko_ = (t) * GBK;                                \
    char* sb_ = lds + sl_ * 28672;                                                     \
    __builtin_amdgcn_global_load_lds((gbl_u32*)(pA0 + ko_),                            \
        (lds_u32*)(sb_ + wid * 1024), 16, 0, 0);                                       \
    __builtin_amdgcn_global_load_lds((gbl_u32*)(pA1 + ko_),                            \
        (lds_u32*)(sb_ + 8192 + wid * 1024), 16, 0, 0);                                \
    __builtin_amdgcn_global_load_lds((gbl_u32*)(pB0 + ko_),                            \
        (lds_u32*)(sb_ + 16384 + wid * 1024), 16, 0, 0);                               \
    if (wid < 4)                                                                       \
      __builtin_amdgcn_global_load_lds((gbl_u32*)(pB2 + ko_),                          \
          (lds_u32*)(sb_ + 24576 + wid * 1024), 16, 0, 0);                             \
  } while (0)

#define COMPUTE(t) do {                                                                \
    const int sl_ = (t) & 3;                                                           \
    const char* sb_ = lds + sl_ * 28672;                                               \
    short8 afr[8], bfr[3];                                                             \
    _Pragma("unroll") for (int mi = 0; mi < 8; ++mi)                                   \
      afr[mi] = *reinterpret_cast<const short8*>(sb_ + arb + mi * 1024);               \
    _Pragma("unroll") for (int ni = 0; ni < 3; ++ni)                                   \
      bfr[ni] = *reinterpret_cast<const short8*>(sb_ + brb + ni * 1024);               \
    __builtin_amdgcn_s_setprio(1);                                                     \
    _Pragma("unroll") for (int mi = 0; mi < 8; ++mi)                                   \
      _Pragma("unroll") for (int ni = 0; ni < 3; ++ni)                                 \
        acc[mi][ni] = __builtin_amdgcn_mfma_f32_16x16x32_bf16(afr[mi], bfr[ni],        \
                                                              acc[mi][ni], 0, 0, 0);   \
    __builtin_amdgcn_s_setprio(0);                                                     \
  } while (0)

#define WAITBAR2(nlo, nhi) do {                                                        \
    if (wid < 4) asm volatile("s_waitcnt vmcnt(" #nlo ")" ::: "memory");               \
    else         asm volatile("s_waitcnt vmcnt(" #nhi ")" ::: "memory");               \
    __builtin_amdgcn_s_barrier();                                                      \
    asm volatile("" ::: "memory");                                                     \
  } while (0)

  const int nt = K / GBK;
  STAGE(0); STAGE(1); STAGE(2);
  for (int t = 0; t < nt - 3; ++t) {
    WAITBAR2(10, 8);
    STAGE(t + 3);
    COMPUTE(t);
  }
  WAITBAR2(10, 8); COMPUTE(nt - 3);
  WAITBAR2(5, 4);  COMPUTE(nt - 2);
  WAITBAR2(0, 0);  COMPUTE(nt - 1);

#undef STAGE
#undef COMPUTE
#undef WAITBAR2

#pragma unroll
  for (int mi = 0; mi < 8; ++mi) {
    const int row0c = by * 256 + wr * 128 + mi * 16 + lg * 4;
#pragma unroll
    for (int ni = 0; ni < 3; ++ni) {
      const int col = bx * 192 + wcn * 48 + ni * 16 + lr;
#pragma unroll
      for (int r = 0; r < 4; ++r) {
        size_t idx = (size_t)(row0c + r) * N + col;
        if (OUT_BF16) ((unsigned short*)Cout)[idx] = f2bf(acc[mi][ni][r]);
        else          ((float*)Cout)[idx] = acc[mi][ni][r];
      }
    }
  }
}

// ---------------- 128x256 BK=64 ring-3 GEMM (proj): full 256-block fill ----------
// R7 skeleton (counted vmcnt, prefetch-2) with doubled K-tile: 32 MFMA + 16
// ds_read_b128 per barrier (was 16+8), barriers halved 64->32. 3-bit both-sides
// swizzle for 128B rows. LDS 3 x 48KB = 144KB.
template<int OUT_BF16>
__global__ __launch_bounds__(512) void k_gemm128b(const unsigned short* __restrict__ A,
                                                  const unsigned short* __restrict__ B,
                                                  void* __restrict__ Cout,
                                                  int M, int N, int K, int nbx) {
  extern __shared__ __align__(16) char lds[];  // 3 slots x (A 16KB + B 32KB)
  const int tid = threadIdx.x, lane = tid & 63, wid = tid >> 6;
  const int lr = lane & 15, lg = lane >> 4;
  const int wr = wid >> 2, wcn = wid & 3;

  const int nwg = gridDim.x, cpx = nwg >> 3;
  const int id = (int)blockIdx.x;
  const int sid = (id & 7) * cpx + (id >> 3);
  const int by = sid / nbx, bx = sid - by * nbx;

  const unsigned short* Ab = A + (size_t)by * 128 * K;
  const unsigned short* Bb = B + (size_t)bx * 256 * K;

  // staging: rows trow + {0,64} (A) / trow + {0,64,128,192} (B); chunk tc of 8 per
  // 128B row; source chunk pre-XORed with row&7 (= trow&7, offsets are mult of 64).
  const int trow = tid >> 3;
  const int tc   = tid & 7;
  const int csw  = (((tc * 16) ^ ((trow & 7) << 4)) >> 1);
  const unsigned short* pA = Ab + (size_t)trow * K + csw;
  const unsigned short* pB = Bb + (size_t)trow * K + csw;

  // read-side: frag row r at r*128 bytes; chunk XOR (lr&7) (frag rows ≡ lr mod 8)
  const int arb = (wr * 64 + lr) * 128;            // + mi*2048 + chS
  const int brb = 16384 + (wcn * 64 + lr) * 128;   // + ni*2048 + chS
  const int ch0 = (lg * 16) ^ ((lr & 7) << 4);
  const int ch1 = (64 + lg * 16) ^ ((lr & 7) << 4);

  f32x4 acc[4][4];
#pragma unroll
  for (int mi = 0; mi < 4; ++mi)
#pragma unroll
    for (int ni = 0; ni < 4; ++ni)
#pragma unroll
      for (int r = 0; r < 4; ++r) acc[mi][ni][r] = 0.f;

#define STAGE(t_, sl_) do {                                                            \
    const unsigned short* at_ = pA + (size_t)(t_) * 64;                                \
    const unsigned short* bt_ = pB + (size_t)(t_) * 64;                                \
    char* sb_ = lds + (sl_) * 49152;                                                   \
    _Pragma("unroll") for (int i = 0; i < 2; ++i)                                      \
      __builtin_amdgcn_global_load_lds((gbl_u32*)(at_ + (size_t)i * 64 * K),           \
          (lds_u32*)(sb_ + i * 8192 + wid * 1024), 16, 0, 0);                          \
    _Pragma("unroll") for (int j = 0; j < 4; ++j)                                      \
      __builtin_amdgcn_global_load_lds((gbl_u32*)(bt_ + (size_t)j * 64 * K),           \
          (lds_u32*)(sb_ + 16384 + j * 8192 + wid * 1024), 16, 0, 0);                  \
  } while (0)

#define COMPUTE(sl_) do {                                                              \
    const char* sb_ = lds + (sl_) * 49152;                                             \
    short8 afr[4][2], bfr[4][2];                                                       \
    _Pragma("unroll") for (int mi = 0; mi < 4; ++mi) {                                 \
      afr[mi][0] = *reinterpret_cast<const short8*>(sb_ + arb + mi * 2048 + ch0);      \
      afr[mi][1] = *reinterpret_cast<const short8*>(sb_ + arb + mi * 2048 + ch1);      \
    }                                                                                  \
    _Pragma("unroll") for (int ni = 0; ni < 4; ++ni) {                                 \
      bfr[ni][0] = *reinterpret_cast<const short8*>(sb_ + brb + ni * 2048 + ch0);      \
      bfr[ni][1] = *reinterpret_cast<const short8*>(sb_ + brb + ni * 2048 + ch1);      \
    }                                                                                  \
    __builtin_amdgcn_s_setprio(1);                                                     \
    _Pragma("unroll") for (int mi = 0; mi < 4; ++mi)                                   \
      _Pragma("unroll") for (int ni = 0; ni < 4; ++ni) {                               \
        f32x4 a_ = acc[mi][ni];                                                        \
        a_ = __builtin_amdgcn_mfma_f32_16x16x32_bf16(afr[mi][0], bfr[ni][0], a_, 0, 0, 0); \
        a_ = __builtin_amdgcn_mfma_f32_16x16x32_bf16(afr[mi][1], bfr[ni][1], a_, 0, 0, 0); \
        acc[mi][ni] = a_;                                                              \
      }                                                                                \
    __builtin_amdgcn_s_setprio(0);                                                     \
  } while (0)

#define WAITBAR(n) do {                                                                \
    asm volatile("s_waitcnt vmcnt(" #n ")" ::: "memory");                              \
    __builtin_amdgcn_s_barrier();                                                      \
    asm volatile("" ::: "memory");                                                     \
  } while (0)

  const int nt = K >> 6;  // 32 K-tiles
  STAGE(0, 0); STAGE(1, 1);
  int sc = 0, ss = 2;
  for (int t = 0; t < nt - 2; ++t) {
    WAITBAR(6);
    STAGE(t + 2, ss);
    COMPUTE(sc);
    sc = (sc == 2) ? 0 : sc + 1;
    ss = (ss == 2) ? 0 : ss + 1;
  }
  WAITBAR(6);
  COMPUTE(sc);
  sc = (sc == 2) ? 0 : sc + 1;
  WAITBAR(0);
  COMPUTE(sc);

#undef STAGE
#undef COMPUTE
#undef WAITBAR

#pragma unroll
  for (int mi = 0; mi < 4; ++mi) {
    const int row0c = by * 128 + wr * 64 + mi * 16 + lg * 4;
#pragma unroll
    for (int ni = 0; ni < 4; ++ni) {
      const int col = bx * 256 + wcn * 64 + ni * 16 + lr;
#pragma unroll
      for (int r = 0; r < 4; ++r) {
        size_t idx = (size_t)(row0c + r) * N + col;
        if (OUT_BF16) ((unsigned short*)Cout)[idx] = f2bf(acc[mi][ni][r]);
        else          ((float*)Cout)[idx] = acc[mi][ni][r];
      }
    }
  }
}

// ---------------- RoPE + RMSNorm (Q,K heads) fused with V transpose ----------------
// blocks [0, NRB): rope jobs; blocks [NRB, NRB+512): V transpose.
#define NRB ((NB * T_SEQ * (NHQ + NHKV)) / 4)
__global__ __launch_bounds__(256) void k_rope_vt(const unsigned short* __restrict__ qkv,
                                                 const float* __restrict__ tbl,
                                                 unsigned short* __restrict__ Qo,
                                                 unsigned short* __restrict__ Ko,
                                                 unsigned short* __restrict__ Vt) {
  __shared__ unsigned short tile[64][65];
  if ((int)blockIdx.x < NRB) {
    const int lane = threadIdx.x & 63, wid = threadIdx.x >> 6;
    const int job = blockIdx.x * 4 + wid;
    const int row = job / 20;
    const int hh  = job - row * 20;
    const int b = row >> 11, t = row & (T_SEQ - 1);
    const unsigned short* src;
    unsigned short* dst;
    float scale;
    if (hh < NHQ) {
      src = qkv + (size_t)row * QKVN + hh * DHD;
      dst = Qo + (((size_t)b * NHQ + hh) * T_SEQ + t) * DHD;
      scale = 0.1275173019f;  // log2(e)/sqrt(128)
    } else {
      int h = hh - NHQ;
      src = qkv + (size_t)row * QKVN + CDIM + h * DHD;
      dst = Ko + (((size_t)b * NHKV + h) * T_SEQ + t) * DHD;
      scale = 1.f;
    }
    unsigned int pr = *reinterpret_cast<const unsigned int*>(src + lane * 2);
    float xe = bf2f(pr & 0xffffu), xo = bf2f(pr >> 16);
    float c = tbl[t * 64 + lane], s = tbl[T_SEQ * 64 + t * 64 + lane];
    float e = xe * c - xo * s;
    float o = xo * c + xe * s;
    float ss = e * e + o * o;
#pragma unroll
    for (int off = 1; off < 64; off <<= 1) ss += __shfl_xor(ss, off);
    float rn = rsqrtf(ss * (1.f / 128.f) + 1.1920929e-07f) * scale;
    unsigned short eb = f2bf(e * rn), ob = f2bf(o * rn);
    *reinterpret_cast<unsigned int*>(dst + lane * 2) = ((unsigned int)ob << 16) | eb;
  } else {
    const int blk = (int)blockIdx.x - NRB;
    const int dt = blk & 1;
    const int tt = (blk >> 1) & 31;
    const int h = (blk >> 6) & 3;
    const int b = blk >> 8;
    const int t0 = tt * 64, d0 = dt * 64;
#pragma unroll
    for (int i = 0; i < 16; ++i) {
      int idx = i * 256 + threadIdx.x;
      int tl = idx >> 6, dl = idx & 63;
      tile[tl][dl] = qkv[(size_t)(b * T_SEQ + t0 + tl) * QKVN + (CDIM + NHKV * DHD) + h * DHD + d0 + dl];
    }
    __syncthreads();
#pragma unroll
    for (int i = 0; i < 16; ++i) {
      int idx = i * 256 + threadIdx.x;
      int dl = idx >> 6, tl = idx & 63;
      Vt[((size_t)(b * NHKV + h) * DHD + d0 + dl) * T_SEQ + t0 + tl] = tile[tl][dl];
    }
  }
}

// ---------------- windowed causal flash attention, LDS-staged K/V ----------------
// R12 measured config: 256-q tile, 8 waves, 3-slot ring, vmcnt(2). DO NOT TOUCH.
__global__ __launch_bounds__(512) void k_attn(const unsigned short* __restrict__ Q,
                                              const unsigned short* __restrict__ K,
                                              const unsigned short* __restrict__ Vt,
                                              unsigned short* __restrict__ Y) {
  __shared__ __align__(16) char lds[65536];  // 3 x 16KB staging ring; 64KB epilogue
  const int tid = threadIdx.x, lane = tid & 63, wid = tid >> 6;
  const int l31 = lane & 31, hi = lane >> 5;

  const int id = (int)blockIdx.x;
  const int sid = (id & 7) * 32 + (id >> 3);
  const int qt = sid & 7;
  const int h = (sid >> 3) & 15;
  const int b = sid >> 7;
  const int hkv = h >> 2;
  const int q0 = qt * 256;
  const int q0g = q0 + wid * 32;

  const unsigned short* Qp = Q + (((size_t)b * NHQ + h) * T_SEQ + q0g) * DHD;
  const char* Kbyte = (const char*)(K + ((size_t)b * NHKV + hkv) * T_SEQ * DHD);
  const char* Vbyte = (const char*)(Vt + ((size_t)b * NHKV + hkv) * DHD * T_SEQ);

  const int ksrc = (tid >> 4) * 256 + (((tid & 15) * 16) ^ (((tid >> 4) & 7) << 4));
  const int vsrc = (tid >> 2) * 4096 + (((tid & 3) * 16) ^ (((tid >> 2) & 3) << 4));

  const int ksw = (l31 & 7) << 4;
  const int vsw = (l31 & 3) << 4;

#define STAGEKV(k0_, sb_) do {                                                           \
    const char* kt_ = Kbyte + (size_t)(k0_) * 256;                                       \
    const char* vt_ = Vbyte + (size_t)(k0_) * 2;                                         \
    __builtin_amdgcn_global_load_lds((gbl_u32*)(kt_ + ksrc),                             \
        (lds_u32*)(lds + (sb_) + wid * 1024), 16, 0, 0);                                 \
    __builtin_amdgcn_global_load_lds((gbl_u32*)(vt_ + vsrc),                             \
        (lds_u32*)(lds + (sb_) + 8192 + wid * 1024), 16, 0, 0);                          \
  } while (0)

  const int kt0 = (q0 >= SWIN) ? ((q0 - (SWIN - 1)) >> 5) : 0;
  const int kth = (q0 + 255) >> 5;

  STAGEKV(kt0 * 32, 0);

  short8 qf[8];
#pragma unroll
  for (int ds = 0; ds < 8; ++ds)
    qf[ds] = *reinterpret_cast<const short8*>(Qp + (size_t)l31 * DHD + ds * 16 + hi * 8);

  f32x16 accO[4];
#pragma unroll
  for (int dt = 0; dt < 4; ++dt)
#pragma unroll
    for (int r = 0; r < 16; ++r) accO[dt][r] = 0.f;
  float m = -1e30f, l = 0.f;
  const int qg = q0g + l31;

  int sl = 0;
  for (int t = kt0; t <= kth; ++t) {
    const int sln = (sl == 2) ? 0 : sl + 1;
    if (t < kth) {
      STAGEKV((t + 1) * 32, sln * 16384);
      asm volatile("s_waitcnt vmcnt(2)" ::: "memory");
    } else {
      asm volatile("s_waitcnt vmcnt(0)" ::: "memory");
    }
    __builtin_amdgcn_s_barrier();

    const int k0 = t * 32;
    if (k0 <= q0g && k0 + 31 >= q0g - (SWIN - 1)) {
      const char* kbase = lds + sl * 16384;
      const char* vbase = kbase + 8192;

      short8 kf[8];
#pragma unroll
      for (int ds = 0; ds < 8; ++ds)
        kf[ds] = *reinterpret_cast<const short8*>(kbase + l31 * 256 + ((ds * 32 + hi * 16) ^ ksw));

      f32x16 s;
#pragma unroll
      for (int r = 0; r < 16; ++r) s[r] = 0.f;
      __builtin_amdgcn_s_setprio(1);
#pragma unroll
      for (int ds = 0; ds < 8; ++ds)
        s = __builtin_amdgcn_mfma_f32_32x32x16_bf16(kf[ds], qf[ds], s, 0, 0, 0);
      __builtin_amdgcn_s_setprio(0);

      if (k0 < q0g - 480 || k0 >= q0g) {
#pragma unroll
        for (int r = 0; r < 16; ++r) {
          int kk = k0 + (r & 3) + 8 * (r >> 2) + 4 * hi;
          if (kk > qg || qg - kk >= SWIN) s[r] = -1e30f;
        }
      }

      float mx[8];
#pragma unroll
      for (int j = 0; j < 8; ++j) mx[j] = fmaxf(s[2 * j], s[2 * j + 1]);
      float a0 = fmaxf(mx[0], mx[1]), a1 = fmaxf(mx[2], mx[3]);
      float a2 = fmaxf(mx[4], mx[5]), a3 = fmaxf(mx[6], mx[7]);
      float tmax = fmaxf(fmaxf(a0, a1), fmaxf(a2, a3));
      tmax = fmaxf(tmax, __shfl_xor(tmax, 32));

      float mn = m;
      if (!__all(tmax <= m + 8.f)) {
        mn = fmaxf(m, tmax);
        float alpha = exp2_fast(m - mn);
        l *= alpha;
#pragma unroll
        for (int dt = 0; dt < 4; ++dt)
#pragma unroll
          for (int r = 0; r < 16; ++r) accO[dt][r] *= alpha;
        m = mn;
      }

#pragma unroll
      for (int r = 0; r < 16; ++r) s[r] = exp2_fast(s[r] - mn);
      float sx[8];
#pragma unroll
      for (int j = 0; j < 8; ++j) sx[j] = s[2 * j] + s[2 * j + 1];
      float b0 = sx[0] + sx[1], b1 = sx[2] + sx[3], b2 = sx[4] + sx[5], b3 = sx[6] + sx[7];
      float ps = (b0 + b1) + (b2 + b3);
      ps += __shfl_xor(ps, 32);
      l += ps;

      unsigned int w[8];
#pragma unroll
      for (int j = 0; j < 8; ++j)
        asm("v_cvt_pk_bf16_f32 %0, %1, %2" : "=v"(w[j]) : "v"(s[2 * j]), "v"(s[2 * j + 1]));
      asm("v_permlane32_swap_b32 %0, %1" : "+v"(w[0]), "+v"(w[2]));
      asm("v_permlane32_swap_b32 %0, %1" : "+v"(w[1]), "+v"(w[3]));
      asm("v_permlane32_swap_b32 %0, %1" : "+v"(w[4]), "+v"(w[6]));
      asm("v_permlane32_swap_b32 %0, %1" : "+v"(w[5]), "+v"(w[7]));
      u32x4 p0 = {w[0], w[1], w[2], w[3]};
      u32x4 p1 = {w[4], w[5], w[6], w[7]};
      short8 pf0 = __builtin_bit_cast(short8, p0);
      short8 pf1 = __builtin_bit_cast(short8, p1);

      __builtin_amdgcn_s_setprio(1);
#pragma unroll
      for (int dt = 0; dt < 4; ++dt) {
        const char* vrow = vbase + (dt * 2048 + l31 * 64);
        short8 vf0 = *reinterpret_cast<const short8*>(vrow + ((hi * 16) ^ vsw));
        short8 vf1 = *reinterpret_cast<const short8*>(vrow + ((32 + hi * 16) ^ vsw));
        accO[dt] = __builtin_amdgcn_mfma_f32_32x32x16_bf16(vf0, pf0, accO[dt], 0, 0, 0);
        accO[dt] = __builtin_amdgcn_mfma_f32_32x32x16_bf16(vf1, pf1, accO[dt], 0, 0, 0);
      }
      __builtin_amdgcn_s_setprio(0);
    }
    sl = sln;
  }
#undef STAGEKV

  __syncthreads();

  float inv = 1.f / l;
  char* obc = lds + wid * 8192;
#pragma unroll
  for (int dt = 0; dt < 4; ++dt)
#pragma unroll
    for (int j = 0; j < 8; ++j) {
      float a = accO[dt][2 * j] * inv, c = accO[dt][2 * j + 1] * inv;
      unsigned int wv;
      asm("v_cvt_pk_bf16_f32 %0, %1, %2" : "=v"(wv) : "v"(a), "v"(c));
      int d = dt * 32 + 2 * (j & 1) + 8 * (j >> 1) + 4 * hi;
      *reinterpret_cast<unsigned int*>(obc + l31 * 256 + ((d * 2) ^ ksw)) = wv;
    }
#pragma unroll
  for (int i = 0; i < 8; ++i) {
    int chunk = i * 64 + lane;
    int row = chunk >> 4, c8 = chunk & 15;
    short8 v = *reinterpret_cast<const short8*>(obc + row * 256 + ((c8 * 16) ^ ((row & 7) << 4)));
    *reinterpret_cast<short8*>(Y + ((size_t)b * T_SEQ + q0g + row) * CDIM + h * DHD + c8 * 8) = v;
  }
}

extern "C" void kernel_launch(void* const* d_in, const int* in_sizes, int n_in,
                              void* d_out, int out_size, void* d_ws, size_t ws_size,
                              hipStream_t stream) {
  const float* x     = (const float*)d_in[0];
  const float* wqkv  = (const float*)d_in[1];
  const float* wproj = (const float*)d_in[2];
  float* out = (float*)d_out;

  char* ws = (char*)d_ws;
  unsigned short* xb     = (unsigned short*)(ws + 0);         // 16 MB (reused as y)
  unsigned short* wqkvb  = (unsigned short*)(ws + 16777216);  // 12 MB
  unsigned short* wprojb = (unsigned short*)(ws + 29360128);  // 8 MB
  unsigned short* qkvb   = (unsigned short*)(ws + 37748736);  // 24 MB
  unsigned short* Qb     = (unsigned short*)(ws + 62914560);  // 16 MB
  unsigned short* Kb     = (unsigned short*)(ws + 79691776);  // 4 MB
  unsigned short* Vtb    = (unsigned short*)(ws + 83886080);  // 4 MB
  float* tbl             = (float*)(ws + 88080384);           // 1 MB
  unsigned short* yb     = xb;

  k_f2bf3t<<<2048, 256, 0, stream>>>(x, xb, (NB * T_SEQ * CDIM) / 4,
                                     wqkv, wqkvb, (QKVN * CDIM) / 4,
                                     wproj, wprojb, (CDIM * CDIM) / 4, tbl);

  // QKV: 256x192 tile -> 256 blocks (exact CU fill)
  k_gemm192<1><<<256, 512, 114688, stream>>>(
      xb, wqkvb, qkvb, NB * T_SEQ, QKVN, CDIM, QKVN / 192);
  // RoPE+RMS (20480 blocks) + V transpose (512 blocks) in one launch
  k_rope_vt<<<NRB + 512, 256, 0, stream>>>(qkvb, tbl, Qb, Kb, Vtb);
  // attn: 256-q tiles, 8 waves -> 256 blocks
  k_attn<<<NB * NHQ * (T_SEQ / 256), 512, 0, stream>>>(Qb, Kb, Vtb, yb);
  // proj: 128x256 tile, BK=64 ring-3 -> 256 blocks (exact CU fill)
  k_gemm128b<0><<<256, 512, 147456, stream>>>(
      yb, wprojb, out, NB * T_SEQ, CDIM, CDIM, CDIM / 256);
}

// Round 14
// 159.335 us; speedup vs baseline: 1.2800x; 1.0108x over previous
//
#include <hip/hip_runtime.h>
#include <stdint.h>

#define T_SEQ 2048
#define NB    2
#define DHD   128
#define NHQ   16
#define NHKV  4
#define SWIN  512
#define CDIM  2048
#define QKVN  3072
#define GBK   32

typedef __attribute__((ext_vector_type(8))) short short8;
typedef __attribute__((ext_vector_type(4))) float f32x4;
typedef __attribute__((ext_vector_type(16))) float f32x16;
typedef __attribute__((ext_vector_type(4))) unsigned int u32x4;
typedef __attribute__((address_space(3))) unsigned int lds_u32;
typedef __attribute__((address_space(1))) const unsigned int gbl_u32;

__device__ __forceinline__ unsigned short f2bf(float f) {
  unsigned int u = __float_as_uint(f);
  u += 0x7fffu + ((u >> 16) & 1u);
  return (unsigned short)(u >> 16);
}
__device__ __forceinline__ float bf2f(unsigned int h) {
  return __uint_as_float(h << 16);
}
__device__ __forceinline__ float exp2_fast(float x) {
  float r;
  asm("v_exp_f32 %0, %1" : "=v"(r) : "v"(x));
  return r;
}

// ---------------- fp32 -> bf16 (x, wqkv, wproj) + RoPE trig table, one launch ----
__global__ __launch_bounds__(256) void k_f2bf3t(const float* __restrict__ a, unsigned short* __restrict__ oa, int na4,
                                                const float* __restrict__ b, unsigned short* __restrict__ ob, int nb4,
                                                const float* __restrict__ c, unsigned short* __restrict__ oc, int nc4,
                                                float* __restrict__ tbl) {
  if (blockIdx.x < 512) {
    int i = blockIdx.x * 256 + threadIdx.x;
    int t = i >> 6, f = i & 63;
    float invf = powf(10000.f, -(float)f * (1.f / 64.f));
    float ang = (float)t * invf;
    tbl[i] = cosf(ang);
    tbl[T_SEQ * 64 + i] = sinf(ang);
  }
  const int n = na4 + nb4 + nc4;
  for (int i = blockIdx.x * 256 + threadIdx.x; i < n; i += gridDim.x * 256) {
    const float* src; unsigned short* dst; int j = i;
    if (j < na4) { src = a; dst = oa; }
    else if (j < na4 + nb4) { j -= na4; src = b; dst = ob; }
    else { j -= na4 + nb4; src = c; dst = oc; }
    float4 v = reinterpret_cast<const float4*>(src)[j];
    uint2 o;
    o.x = ((unsigned int)f2bf(v.y) << 16) | f2bf(v.x);
    o.y = ((unsigned int)f2bf(v.w) << 16) | f2bf(v.z);
    reinterpret_cast<uint2*>(dst)[j] = o;
  }
}

// ---------------- 256x192 ring-4 GEMM (QKV): full 256-block fill ----------------
// R10 template; R14: wave layout 2Mx4N -> 4Mx2N (wave tile 64x96). LDS read
// traffic per block 5.5 -> 5.0 MB (A re-read 4x->2x, B 2x->4x; A is larger).
// Staging/swizzle/vmcnt identical (all row bases = 0 mod 8, phases preserved).
template<int OUT_BF16>
__global__ __launch_bounds__(512, 2) void k_gemm192(const unsigned short* __restrict__ A,
                                                    const unsigned short* __restrict__ B,
                                                    void* __restrict__ Cout,
                                                    int M, int N, int K, int nbx) {
  extern __shared__ __align__(16) char lds[];  // 4 slots x (A 16KB + B 12KB) = 112 KiB
  const int tid = threadIdx.x, lane = tid & 63, wid = tid >> 6;
  const int lr = lane & 15, lg = lane >> 4;
  const int wr = wid >> 1, wcn = wid & 1;   // 4M x 2N

  const int nwg = gridDim.x, cpx = nwg >> 3;
  const int id = (int)blockIdx.x;
  const int sid = (id & 7) * cpx + (id >> 3);
  const int by = sid / nbx, bx = sid - by * nbx;

  const unsigned short* Ab = A + (size_t)by * 256 * K;
  const unsigned short* Bb = B + (size_t)bx * 192 * K;

  const int row0 = tid >> 2;
  const int blk  = tid & 3;
  const int col0 = ((blk * 16) ^ (((row0 >> 1) & 3) << 4)) >> 1;
  const unsigned short* pA0 = Ab + (size_t)row0 * K + col0;
  const unsigned short* pA1 = pA0 + (size_t)128 * K;
  const unsigned short* pB0 = Bb + (size_t)row0 * K + col0;
  const unsigned short* pB2 = pB0 + (size_t)128 * K;

  const int sw  = ((lg ^ ((lr >> 1) & 3)) << 4);
  const int arb = (wr * 64 + lr) * 64 + sw;             // + mi*1024, mi<4
  const int brb = 16384 + (wcn * 96 + lr) * 64 + sw;    // + ni*1024, ni<6

  f32x4 acc[4][6];
#pragma unroll
  for (int mi = 0; mi < 4; ++mi)
#pragma unroll
    for (int ni = 0; ni < 6; ++ni)
#pragma unroll
      for (int r = 0; r < 4; ++r) acc[mi][ni][r] = 0.f;

#define STAGE(t) do {                                                                  \
    const int sl_ = (t) & 3; const int ko_ = (t) * GBK;                                \
    char* sb_ = lds + sl_ * 28672;                                                     \
    __builtin_amdgcn_global_load_lds((gbl_u32*)(pA0 + ko_),                            \
        (lds_u32*)(sb_ + wid * 1024), 16, 0, 0);                                       \
    __builtin_amdgcn_global_load_lds((gbl_u32*)(pA1 + ko_),                            \
        (lds_u32*)(sb_ + 8192 + wid * 1024), 16, 0, 0);                                \
    __builtin_amdgcn_global_load_lds((gbl_u32*)(pB0 + ko_),                            \
        (lds_u32*)(sb_ + 16384 + wid * 1024), 16, 0, 0);                               \
    if (wid < 4)                                                                       \
      __builtin_amdgcn_global_load_lds((gbl_u32*)(pB2 + ko_),                          \
          (lds_u32*)(sb_ + 24576 + wid * 1024), 16, 0, 0);                             \
  } while (0)

#define COMPUTE(t) do {                                                                \
    const int sl_ = (t) & 3;                                                           \
    const char* sb_ = lds + sl_ * 28672;                                               \
    short8 afr[4], bfr[6];                                                             \
    _Pragma("unroll") for (int mi = 0; mi < 4; ++mi)                                   \
      afr[mi] = *reinterpret_cast<const short8*>(sb_ + arb + mi * 1024);               \
    _Pragma("unroll") for (int ni = 0; ni < 6; ++ni)                                   \
      bfr[ni] = *reinterpret_cast<const short8*>(sb_ + brb + ni * 1024);               \
    __builtin_amdgcn_s_setprio(1);                                                     \
    _Pragma("unroll") for (int mi = 0; mi < 4; ++mi)                                   \
      _Pragma("unroll") for (int ni = 0; ni < 6; ++ni)                                 \
        acc[mi][ni] = __builtin_amdgcn_mfma_f32_16x16x32_bf16(afr[mi], bfr[ni],        \
                                                              acc[mi][ni], 0, 0, 0);   \
    __builtin_amdgcn_s_setprio(0);                                                     \
  } while (0)

#define WAITBAR2(nlo, nhi) do {                                                        \
    if (wid < 4) asm volatile("s_waitcnt vmcnt(" #nlo ")" ::: "memory");               \
    else         asm volatile("s_waitcnt vmcnt(" #nhi ")" ::: "memory");               \
    __builtin_amdgcn_s_barrier();                                                      \
    asm volatile("" ::: "memory");                                                     \
  } while (0)

  const int nt = K / GBK;
  STAGE(0); STAGE(1); STAGE(2);
  for (int t = 0; t < nt - 3; ++t) {
    WAITBAR2(10, 8);
    STAGE(t + 3);
    COMPUTE(t);
  }
  WAITBAR2(10, 8); COMPUTE(nt - 3);
  WAITBAR2(5, 4);  COMPUTE(nt - 2);
  WAITBAR2(0, 0);  COMPUTE(nt - 1);

#undef STAGE
#undef COMPUTE
#undef WAITBAR2

#pragma unroll
  for (int mi = 0; mi < 4; ++mi) {
    const int row0c = by * 256 + wr * 64 + mi * 16 + lg * 4;
#pragma unroll
    for (int ni = 0; ni < 6; ++ni) {
      const int col = bx * 192 + wcn * 96 + ni * 16 + lr;
#pragma unroll
      for (int r = 0; r < 4; ++r) {
        size_t idx = (size_t)(row0c + r) * N + col;
        if (OUT_BF16) ((unsigned short*)Cout)[idx] = f2bf(acc[mi][ni][r]);
        else          ((float*)Cout)[idx] = acc[mi][ni][r];
      }
    }
  }
}

// ---------------- 128x256 BK=64 ring-3 GEMM (proj): full 256-block fill ----------
// R13 measured config. DO NOT TOUCH.
template<int OUT_BF16>
__global__ __launch_bounds__(512) void k_gemm128b(const unsigned short* __restrict__ A,
                                                  const unsigned short* __restrict__ B,
                                                  void* __restrict__ Cout,
                                                  int M, int N, int K, int nbx) {
  extern __shared__ __align__(16) char lds[];  // 3 slots x (A 16KB + B 32KB)
  const int tid = threadIdx.x, lane = tid & 63, wid = tid >> 6;
  const int lr = lane & 15, lg = lane >> 4;
  const int wr = wid >> 2, wcn = wid & 3;

  const int nwg = gridDim.x, cpx = nwg >> 3;
  const int id = (int)blockIdx.x;
  const int sid = (id & 7) * cpx + (id >> 3);
  const int by = sid / nbx, bx = sid - by * nbx;

  const unsigned short* Ab = A + (size_t)by * 128 * K;
  const unsigned short* Bb = B + (size_t)bx * 256 * K;

  const int trow = tid >> 3;
  const int tc   = tid & 7;
  const int csw  = (((tc * 16) ^ ((trow & 7) << 4)) >> 1);
  const unsigned short* pA = Ab + (size_t)trow * K + csw;
  const unsigned short* pB = Bb + (size_t)trow * K + csw;

  const int arb = (wr * 64 + lr) * 128;
  const int brb = 16384 + (wcn * 64 + lr) * 128;
  const int ch0 = (lg * 16) ^ ((lr & 7) << 4);
  const int ch1 = (64 + lg * 16) ^ ((lr & 7) << 4);

  f32x4 acc[4][4];
#pragma unroll
  for (int mi = 0; mi < 4; ++mi)
#pragma unroll
    for (int ni = 0; ni < 4; ++ni)
#pragma unroll
      for (int r = 0; r < 4; ++r) acc[mi][ni][r] = 0.f;

#define STAGE(t_, sl_) do {                                                            \
    const unsigned short* at_ = pA + (size_t)(t_) * 64;                                \
    const unsigned short* bt_ = pB + (size_t)(t_) * 64;                                \
    char* sb_ = lds + (sl_) * 49152;                                                   \
    _Pragma("unroll") for (int i = 0; i < 2; ++i)                                      \
      __builtin_amdgcn_global_load_lds((gbl_u32*)(at_ + (size_t)i * 64 * K),           \
          (lds_u32*)(sb_ + i * 8192 + wid * 1024), 16, 0, 0);                          \
    _Pragma("unroll") for (int j = 0; j < 4; ++j)                                      \
      __builtin_amdgcn_global_load_lds((gbl_u32*)(bt_ + (size_t)j * 64 * K),           \
          (lds_u32*)(sb_ + 16384 + j * 8192 + wid * 1024), 16, 0, 0);                  \
  } while (0)

#define COMPUTE(sl_) do {                                                              \
    const char* sb_ = lds + (sl_) * 49152;                                             \
    short8 afr[4][2], bfr[4][2];                                                       \
    _Pragma("unroll") for (int mi = 0; mi < 4; ++mi) {                                 \
      afr[mi][0] = *reinterpret_cast<const short8*>(sb_ + arb + mi * 2048 + ch0);      \
      afr[mi][1] = *reinterpret_cast<const short8*>(sb_ + arb + mi * 2048 + ch1);      \
    }                                                                                  \
    _Pragma("unroll") for (int ni = 0; ni < 4; ++ni) {                                 \
      bfr[ni][0] = *reinterpret_cast<const short8*>(sb_ + brb + ni * 2048 + ch0);      \
      bfr[ni][1] = *reinterpret_cast<const short8*>(sb_ + brb + ni * 2048 + ch1);      \
    }                                                                                  \
    __builtin_amdgcn_s_setprio(1);                                                     \
    _Pragma("unroll") for (int mi = 0; mi < 4; ++mi)                                   \
      _Pragma("unroll") for (int ni = 0; ni < 4; ++ni) {                               \
        f32x4 a_ = acc[mi][ni];                                                        \
        a_ = __builtin_amdgcn_mfma_f32_16x16x32_bf16(afr[mi][0], bfr[ni][0], a_, 0, 0, 0); \
        a_ = __builtin_amdgcn_mfma_f32_16x16x32_bf16(afr[mi][1], bfr[ni][1], a_, 0, 0, 0); \
        acc[mi][ni] = a_;                                                              \
      }                                                                                \
    __builtin_amdgcn_s_setprio(0);                                                     \
  } while (0)

#define WAITBAR(n) do {                                                                \
    asm volatile("s_waitcnt vmcnt(" #n ")" ::: "memory");                              \
    __builtin_amdgcn_s_barrier();                                                      \
    asm volatile("" ::: "memory");                                                     \
  } while (0)

  const int nt = K >> 6;
  STAGE(0, 0); STAGE(1, 1);
  int sc = 0, ss = 2;
  for (int t = 0; t < nt - 2; ++t) {
    WAITBAR(6);
    STAGE(t + 2, ss);
    COMPUTE(sc);
    sc = (sc == 2) ? 0 : sc + 1;
    ss = (ss == 2) ? 0 : ss + 1;
  }
  WAITBAR(6);
  COMPUTE(sc);
  sc = (sc == 2) ? 0 : sc + 1;
  WAITBAR(0);
  COMPUTE(sc);

#undef STAGE
#undef COMPUTE
#undef WAITBAR

#pragma unroll
  for (int mi = 0; mi < 4; ++mi) {
    const int row0c = by * 128 + wr * 64 + mi * 16 + lg * 4;
#pragma unroll
    for (int ni = 0; ni < 4; ++ni) {
      const int col = bx * 256 + wcn * 64 + ni * 16 + lr;
#pragma unroll
      for (int r = 0; r < 4; ++r) {
        size_t idx = (size_t)(row0c + r) * N + col;
        if (OUT_BF16) ((unsigned short*)Cout)[idx] = f2bf(acc[mi][ni][r]);
        else          ((float*)Cout)[idx] = acc[mi][ni][r];
      }
    }
  }
}

// ---------------- RoPE + RMSNorm (Q,K heads) fused with V transpose ----------------
#define NRB ((NB * T_SEQ * (NHQ + NHKV)) / 4)
__global__ __launch_bounds__(256) void k_rope_vt(const unsigned short* __restrict__ qkv,
                                                 const float* __restrict__ tbl,
                                                 unsigned short* __restrict__ Qo,
                                                 unsigned short* __restrict__ Ko,
                                                 unsigned short* __restrict__ Vt) {
  __shared__ unsigned short tile[64][65];
  if ((int)blockIdx.x < NRB) {
    const int lane = threadIdx.x & 63, wid = threadIdx.x >> 6;
    const int job = blockIdx.x * 4 + wid;
    const int row = job / 20;
    const int hh  = job - row * 20;
    const int b = row >> 11, t = row & (T_SEQ - 1);
    const unsigned short* src;
    unsigned short* dst;
    float scale;
    if (hh < NHQ) {
      src = qkv + (size_t)row * QKVN + hh * DHD;
      dst = Qo + (((size_t)b * NHQ + hh) * T_SEQ + t) * DHD;
      scale = 0.1275173019f;  // log2(e)/sqrt(128)
    } else {
      int h = hh - NHQ;
      src = qkv + (size_t)row * QKVN + CDIM + h * DHD;
      dst = Ko + (((size_t)b * NHKV + h) * T_SEQ + t) * DHD;
      scale = 1.f;
    }
    unsigned int pr = *reinterpret_cast<const unsigned int*>(src + lane * 2);
    float xe = bf2f(pr & 0xffffu), xo = bf2f(pr >> 16);
    float c = tbl[t * 64 + lane], s = tbl[T_SEQ * 64 + t * 64 + lane];
    float e = xe * c - xo * s;
    float o = xo * c + xe * s;
    float ss = e * e + o * o;
#pragma unroll
    for (int off = 1; off < 64; off <<= 1) ss += __shfl_xor(ss, off);
    float rn = rsqrtf(ss * (1.f / 128.f) + 1.1920929e-07f) * scale;
    unsigned short eb = f2bf(e * rn), ob = f2bf(o * rn);
    *reinterpret_cast<unsigned int*>(dst + lane * 2) = ((unsigned int)ob << 16) | eb;
  } else {
    const int blk = (int)blockIdx.x - NRB;
    const int dt = blk & 1;
    const int tt = (blk >> 1) & 31;
    const int h = (blk >> 6) & 3;
    const int b = blk >> 8;
    const int t0 = tt * 64, d0 = dt * 64;
#pragma unroll
    for (int i = 0; i < 16; ++i) {
      int idx = i * 256 + threadIdx.x;
      int tl = idx >> 6, dl = idx & 63;
      tile[tl][dl] = qkv[(size_t)(b * T_SEQ + t0 + tl) * QKVN + (CDIM + NHKV * DHD) + h * DHD + d0 + dl];
    }
    __syncthreads();
#pragma unroll
    for (int i = 0; i < 16; ++i) {
      int idx = i * 256 + threadIdx.x;
      int dl = idx >> 6, tl = idx & 63;
      Vt[((size_t)(b * NHKV + h) * DHD + d0 + dl) * T_SEQ + t0 + tl] = tile[tl][dl];
    }
  }
}

// ---------------- windowed causal flash attention, LDS-staged K/V ----------------
// R12 measured config. DO NOT TOUCH.
__global__ __launch_bounds__(512) void k_attn(const unsigned short* __restrict__ Q,
                                              const unsigned short* __restrict__ K,
                                              const unsigned short* __restrict__ Vt,
                                              unsigned short* __restrict__ Y) {
  __shared__ __align__(16) char lds[65536];
  const int tid = threadIdx.x, lane = tid & 63, wid = tid >> 6;
  const int l31 = lane & 31, hi = lane >> 5;

  const int id = (int)blockIdx.x;
  const int sid = (id & 7) * 32 + (id >> 3);
  const int qt = sid & 7;
  const int h = (sid >> 3) & 15;
  const int b = sid >> 7;
  const int hkv = h >> 2;
  const int q0 = qt * 256;
  const int q0g = q0 + wid * 32;

  const unsigned short* Qp = Q + (((size_t)b * NHQ + h) * T_SEQ + q0g) * DHD;
  const char* Kbyte = (const char*)(K + ((size_t)b * NHKV + hkv) * T_SEQ * DHD);
  const char* Vbyte = (const char*)(Vt + ((size_t)b * NHKV + hkv) * DHD * T_SEQ);

  const int ksrc = (tid >> 4) * 256 + (((tid & 15) * 16) ^ (((tid >> 4) & 7) << 4));
  const int vsrc = (tid >> 2) * 4096 + (((tid & 3) * 16) ^ (((tid >> 2) & 3) << 4));

  const int ksw = (l31 & 7) << 4;
  const int vsw = (l31 & 3) << 4;

#define STAGEKV(k0_, sb_) do {                                                           \
    const char* kt_ = Kbyte + (size_t)(k0_) * 256;                                       \
    const char* vt_ = Vbyte + (size_t)(k0_) * 2;                                         \
    __builtin_amdgcn_global_load_lds((gbl_u32*)(kt_ + ksrc),                             \
        (lds_u32*)(lds + (sb_) + wid * 1024), 16, 0, 0);                                 \
    __builtin_amdgcn_global_load_lds((gbl_u32*)(vt_ + vsrc),                             \
        (lds_u32*)(lds + (sb_) + 8192 + wid * 1024), 16, 0, 0);                          \
  } while (0)

  const int kt0 = (q0 >= SWIN) ? ((q0 - (SWIN - 1)) >> 5) : 0;
  const int kth = (q0 + 255) >> 5;

  STAGEKV(kt0 * 32, 0);

  short8 qf[8];
#pragma unroll
  for (int ds = 0; ds < 8; ++ds)
    qf[ds] = *reinterpret_cast<const short8*>(Qp + (size_t)l31 * DHD + ds * 16 + hi * 8);

  f32x16 accO[4];
#pragma unroll
  for (int dt = 0; dt < 4; ++dt)
#pragma unroll
    for (int r = 0; r < 16; ++r) accO[dt][r] = 0.f;
  float m = -1e30f, l = 0.f;
  const int qg = q0g + l31;

  int sl = 0;
  for (int t = kt0; t <= kth; ++t) {
    const int sln = (sl == 2) ? 0 : sl + 1;
    if (t < kth) {
      STAGEKV((t + 1) * 32, sln * 16384);
      asm volatile("s_waitcnt vmcnt(2)" ::: "memory");
    } else {
      asm volatile("s_waitcnt vmcnt(0)" ::: "memory");
    }
    __builtin_amdgcn_s_barrier();

    const int k0 = t * 32;
    if (k0 <= q0g && k0 + 31 >= q0g - (SWIN - 1)) {
      const char* kbase = lds + sl * 16384;
      const char* vbase = kbase + 8192;

      short8 kf[8];
#pragma unroll
      for (int ds = 0; ds < 8; ++ds)
        kf[ds] = *reinterpret_cast<const short8*>(kbase + l31 * 256 + ((ds * 32 + hi * 16) ^ ksw));

      f32x16 s;
#pragma unroll
      for (int r = 0; r < 16; ++r) s[r] = 0.f;
      __builtin_amdgcn_s_setprio(1);
#pragma unroll
      for (int ds = 0; ds < 8; ++ds)
        s = __builtin_amdgcn_mfma_f32_32x32x16_bf16(kf[ds], qf[ds], s, 0, 0, 0);
      __builtin_amdgcn_s_setprio(0);

      if (k0 < q0g - 480 || k0 >= q0g) {
#pragma unroll
        for (int r = 0; r < 16; ++r) {
          int kk = k0 + (r & 3) + 8 * (r >> 2) + 4 * hi;
          if (kk > qg || qg - kk >= SWIN) s[r] = -1e30f;
        }
      }

      float mx[8];
#pragma unroll
      for (int j = 0; j < 8; ++j) mx[j] = fmaxf(s[2 * j], s[2 * j + 1]);
      float a0 = fmaxf(mx[0], mx[1]), a1 = fmaxf(mx[2], mx[3]);
      float a2 = fmaxf(mx[4], mx[5]), a3 = fmaxf(mx[6], mx[7]);
      float tmax = fmaxf(fmaxf(a0, a1), fmaxf(a2, a3));
      tmax = fmaxf(tmax, __shfl_xor(tmax, 32));

      float mn = m;
      if (!__all(tmax <= m + 8.f)) {
        mn = fmaxf(m, tmax);
        float alpha = exp2_fast(m - mn);
        l *= alpha;
#pragma unroll
        for (int dt = 0; dt < 4; ++dt)
#pragma unroll
          for (int r = 0; r < 16; ++r) accO[dt][r] *= alpha;
        m = mn;
      }

#pragma unroll
      for (int r = 0; r < 16; ++r) s[r] = exp2_fast(s[r] - mn);
      float sx[8];
#pragma unroll
      for (int j = 0; j < 8; ++j) sx[j] = s[2 * j] + s[2 * j + 1];
      float b0 = sx[0] + sx[1], b1 = sx[2] + sx[3], b2 = sx[4] + sx[5], b3 = sx[6] + sx[7];
      float ps = (b0 + b1) + (b2 + b3);
      ps += __shfl_xor(ps, 32);
      l += ps;

      unsigned int w[8];
#pragma unroll
      for (int j = 0; j < 8; ++j)
        asm("v_cvt_pk_bf16_f32 %0, %1, %2" : "=v"(w[j]) : "v"(s[2 * j]), "v"(s[2 * j + 1]));
      asm("v_permlane32_swap_b32 %0, %1" : "+v"(w[0]), "+v"(w[2]));
      asm("v_permlane32_swap_b32 %0, %1" : "+v"(w[1]), "+v"(w[3]));
      asm("v_permlane32_swap_b32 %0, %1" : "+v"(w[4]), "+v"(w[6]));
      asm("v_permlane32_swap_b32 %0, %1" : "+v"(w[5]), "+v"(w[7]));
      u32x4 p0 = {w[0], w[1], w[2], w[3]};
      u32x4 p1 = {w[4], w[5], w[6], w[7]};
      short8 pf0 = __builtin_bit_cast(short8, p0);
      short8 pf1 = __builtin_bit_cast(short8, p1);

      __builtin_amdgcn_s_setprio(1);
#pragma unroll
      for (int dt = 0; dt < 4; ++dt) {
        const char* vrow = vbase + (dt * 2048 + l31 * 64);
        short8 vf0 = *reinterpret_cast<const short8*>(vrow + ((hi * 16) ^ vsw));
        short8 vf1 = *reinterpret_cast<const short8*>(vrow + ((32 + hi * 16) ^ vsw));
        accO[dt] = __builtin_amdgcn_mfma_f32_32x32x16_bf16(vf0, pf0, accO[dt], 0, 0, 0);
        accO[dt] = __builtin_amdgcn_mfma_f32_32x32x16_bf16(vf1, pf1, accO[dt], 0, 0, 0);
      }
      __builtin_amdgcn_s_setprio(0);
    }
    sl = sln;
  }
#undef STAGEKV

  __syncthreads();

  float inv = 1.f / l;
  char* obc = lds + wid * 8192;
#pragma unroll
  for (int dt = 0; dt < 4; ++dt)
#pragma unroll
    for (int j = 0; j < 8; ++j) {
      float a = accO[dt][2 * j] * inv, c = accO[dt][2 * j + 1] * inv;
      unsigned int wv;
      asm("v_cvt_pk_bf16_f32 %0, %1, %2" : "=v"(wv) : "v"(a), "v"(c));
      int d = dt * 32 + 2 * (j & 1) + 8 * (j >> 1) + 4 * hi;
      *reinterpret_cast<unsigned int*>(obc + l31 * 256 + ((d * 2) ^ ksw)) = wv;
    }
#pragma unroll
  for (int i = 0; i < 8; ++i) {
    int chunk = i * 64 + lane;
    int row = chunk >> 4, c8 = chunk & 15;
    short8 v = *reinterpret_cast<const short8*>(obc + row * 256 + ((c8 * 16) ^ ((row & 7) << 4)));
    *reinterpret_cast<short8*>(Y + ((size_t)b * T_SEQ + q0g + row) * CDIM + h * DHD + c8 * 8) = v;
  }
}

extern "C" void kernel_launch(void* const* d_in, const int* in_sizes, int n_in,
                              void* d_out, int out_size, void* d_ws, size_t ws_size,
                              hipStream_t stream) {
  const float* x     = (const float*)d_in[0];
  const float* wqkv  = (const float*)d_in[1];
  const float* wproj = (const float*)d_in[2];
  float* out = (float*)d_out;

  char* ws = (char*)d_ws;
  unsigned short* xb     = (unsigned short*)(ws + 0);         // 16 MB (reused as y)
  unsigned short* wqkvb  = (unsigned short*)(ws + 16777216);  // 12 MB
  unsigned short* wprojb = (unsigned short*)(ws + 29360128);  // 8 MB
  unsigned short* qkvb   = (unsigned short*)(ws + 37748736);  // 24 MB
  unsigned short* Qb     = (unsigned short*)(ws + 62914560);  // 16 MB
  unsigned short* Kb     = (unsigned short*)(ws + 79691776);  // 4 MB
  unsigned short* Vtb    = (unsigned short*)(ws + 83886080);  // 4 MB
  float* tbl             = (float*)(ws + 88080384);           // 1 MB
  unsigned short* yb     = xb;

  k_f2bf3t<<<2048, 256, 0, stream>>>(x, xb, (NB * T_SEQ * CDIM) / 4,
                                     wqkv, wqkvb, (QKVN * CDIM) / 4,
                                     wproj, wprojb, (CDIM * CDIM) / 4, tbl);

  k_gemm192<1><<<256, 512, 114688, stream>>>(
      xb, wqkvb, qkvb, NB * T_SEQ, QKVN, CDIM, QKVN / 192);
  k_rope_vt<<<NRB + 512, 256, 0, stream>>>(qkvb, tbl, Qb, Kb, Vtb);
  k_attn<<<NB * NHQ * (T_SEQ / 256), 512, 0, stream>>>(Qb, Kb, Vtb, yb);
  k_gemm128b<0><<<256, 512, 147456, stream>>>(
      yb, wprojb, out, NB * T_SEQ, CDIM, CDIM, CDIM / 256);
}

// Round 15
// 159.287 us; speedup vs baseline: 1.2804x; 1.0003x over previous
//
#include <hip/hip_runtime.h>
#include <stdint.h>

#define T_SEQ 2048
#define NB    2
#define DHD   128
#define NHQ   16
#define NHKV  4
#define SWIN  512
#define CDIM  2048
#define QKVN  3072
#define GBK   32

typedef __attribute__((ext_vector_type(8))) short short8;
typedef __attribute__((ext_vector_type(4))) float f32x4;
typedef __attribute__((ext_vector_type(16))) float f32x16;
typedef __attribute__((ext_vector_type(4))) unsigned int u32x4;
typedef __attribute__((address_space(3))) unsigned int lds_u32;
typedef __attribute__((address_space(1))) const unsigned int gbl_u32;

__device__ __forceinline__ unsigned short f2bf(float f) {
  unsigned int u = __float_as_uint(f);
  u += 0x7fffu + ((u >> 16) & 1u);
  return (unsigned short)(u >> 16);
}
__device__ __forceinline__ float bf2f(unsigned int h) {
  return __uint_as_float(h << 16);
}
__device__ __forceinline__ float exp2_fast(float x) {
  float r;
  asm("v_exp_f32 %0, %1" : "=v"(r) : "v"(x));
  return r;
}

// ---------------- fp32 -> bf16 (x, wqkv, wproj) + RoPE trig table, one launch ----
__global__ __launch_bounds__(256) void k_f2bf3t(const float* __restrict__ a, unsigned short* __restrict__ oa, int na4,
                                                const float* __restrict__ b, unsigned short* __restrict__ ob, int nb4,
                                                const float* __restrict__ c, unsigned short* __restrict__ oc, int nc4,
                                                float* __restrict__ tbl) {
  if (blockIdx.x < 512) {
    int i = blockIdx.x * 256 + threadIdx.x;
    int t = i >> 6, f = i & 63;
    float invf = powf(10000.f, -(float)f * (1.f / 64.f));
    float ang = (float)t * invf;
    tbl[i] = cosf(ang);
    tbl[T_SEQ * 64 + i] = sinf(ang);
  }
  const int n = na4 + nb4 + nc4;
  for (int i = blockIdx.x * 256 + threadIdx.x; i < n; i += gridDim.x * 256) {
    const float* src; unsigned short* dst; int j = i;
    if (j < na4) { src = a; dst = oa; }
    else if (j < na4 + nb4) { j -= na4; src = b; dst = ob; }
    else { j -= na4 + nb4; src = c; dst = oc; }
    float4 v = reinterpret_cast<const float4*>(src)[j];
    uint2 o;
    o.x = ((unsigned int)f2bf(v.y) << 16) | f2bf(v.x);
    o.y = ((unsigned int)f2bf(v.w) << 16) | f2bf(v.z);
    reinterpret_cast<uint2*>(dst)[j] = o;
  }
}

// ---------------- 256x192 ring-4 GEMM (QKV), 4Mx2N waves. DO NOT TOUCH ----------
template<int OUT_BF16>
__global__ __launch_bounds__(512, 2) void k_gemm192(const unsigned short* __restrict__ A,
                                                    const unsigned short* __restrict__ B,
                                                    void* __restrict__ Cout,
                                                    int M, int N, int K, int nbx) {
  extern __shared__ __align__(16) char lds[];  // 4 slots x (A 16KB + B 12KB) = 112 KiB
  const int tid = threadIdx.x, lane = tid & 63, wid = tid >> 6;
  const int lr = lane & 15, lg = lane >> 4;
  const int wr = wid >> 1, wcn = wid & 1;   // 4M x 2N

  const int nwg = gridDim.x, cpx = nwg >> 3;
  const int id = (int)blockIdx.x;
  const int sid = (id & 7) * cpx + (id >> 3);
  const int by = sid / nbx, bx = sid - by * nbx;

  const unsigned short* Ab = A + (size_t)by * 256 * K;
  const unsigned short* Bb = B + (size_t)bx * 192 * K;

  const int row0 = tid >> 2;
  const int blk  = tid & 3;
  const int col0 = ((blk * 16) ^ (((row0 >> 1) & 3) << 4)) >> 1;
  const unsigned short* pA0 = Ab + (size_t)row0 * K + col0;
  const unsigned short* pA1 = pA0 + (size_t)128 * K;
  const unsigned short* pB0 = Bb + (size_t)row0 * K + col0;
  const unsigned short* pB2 = pB0 + (size_t)128 * K;

  const int sw  = ((lg ^ ((lr >> 1) & 3)) << 4);
  const int arb = (wr * 64 + lr) * 64 + sw;
  const int brb = 16384 + (wcn * 96 + lr) * 64 + sw;

  f32x4 acc[4][6];
#pragma unroll
  for (int mi = 0; mi < 4; ++mi)
#pragma unroll
    for (int ni = 0; ni < 6; ++ni)
#pragma unroll
      for (int r = 0; r < 4; ++r) acc[mi][ni][r] = 0.f;

#define STAGE(t) do {                                                                  \
    const int sl_ = (t) & 3; const int ko_ = (t) * GBK;                                \
    char* sb_ = lds + sl_ * 28672;                                                     \
    __builtin_amdgcn_global_load_lds((gbl_u32*)(pA0 + ko_),                            \
        (lds_u32*)(sb_ + wid * 1024), 16, 0, 0);                                       \
    __builtin_amdgcn_global_load_lds((gbl_u32*)(pA1 + ko_),                            \
        (lds_u32*)(sb_ + 8192 + wid * 1024), 16, 0, 0);                                \
    __builtin_amdgcn_global_load_lds((gbl_u32*)(pB0 + ko_),                            \
        (lds_u32*)(sb_ + 16384 + wid * 1024), 16, 0, 0);                               \
    if (wid < 4)                                                                       \
      __builtin_amdgcn_global_load_lds((gbl_u32*)(pB2 + ko_),                          \
          (lds_u32*)(sb_ + 24576 + wid * 1024), 16, 0, 0);                             \
  } while (0)

#define COMPUTE(t) do {                                                                \
    const int sl_ = (t) & 3;                                                           \
    const char* sb_ = lds + sl_ * 28672;                                               \
    short8 afr[4], bfr[6];                                                             \
    _Pragma("unroll") for (int mi = 0; mi < 4; ++mi)                                   \
      afr[mi] = *reinterpret_cast<const short8*>(sb_ + arb + mi * 1024);               \
    _Pragma("unroll") for (int ni = 0; ni < 6; ++ni)                                   \
      bfr[ni] = *reinterpret_cast<const short8*>(sb_ + brb + ni * 1024);               \
    __builtin_amdgcn_s_setprio(1);                                                     \
    _Pragma("unroll") for (int mi = 0; mi < 4; ++mi)                                   \
      _Pragma("unroll") for (int ni = 0; ni < 6; ++ni)                                 \
        acc[mi][ni] = __builtin_amdgcn_mfma_f32_16x16x32_bf16(afr[mi], bfr[ni],        \
                                                              acc[mi][ni], 0, 0, 0);   \
    __builtin_amdgcn_s_setprio(0);                                                     \
  } while (0)

#define WAITBAR2(nlo, nhi) do {                                                        \
    if (wid < 4) asm volatile("s_waitcnt vmcnt(" #nlo ")" ::: "memory");               \
    else         asm volatile("s_waitcnt vmcnt(" #nhi ")" ::: "memory");               \
    __builtin_amdgcn_s_barrier();                                                      \
    asm volatile("" ::: "memory");                                                     \
  } while (0)

  const int nt = K / GBK;
  STAGE(0); STAGE(1); STAGE(2);
  for (int t = 0; t < nt - 3; ++t) {
    WAITBAR2(10, 8);
    STAGE(t + 3);
    COMPUTE(t);
  }
  WAITBAR2(10, 8); COMPUTE(nt - 3);
  WAITBAR2(5, 4);  COMPUTE(nt - 2);
  WAITBAR2(0, 0);  COMPUTE(nt - 1);

#undef STAGE
#undef COMPUTE
#undef WAITBAR2

#pragma unroll
  for (int mi = 0; mi < 4; ++mi) {
    const int row0c = by * 256 + wr * 64 + mi * 16 + lg * 4;
#pragma unroll
    for (int ni = 0; ni < 6; ++ni) {
      const int col = bx * 192 + wcn * 96 + ni * 16 + lr;
#pragma unroll
      for (int r = 0; r < 4; ++r) {
        size_t idx = (size_t)(row0c + r) * N + col;
        if (OUT_BF16) ((unsigned short*)Cout)[idx] = f2bf(acc[mi][ni][r]);
        else          ((float*)Cout)[idx] = acc[mi][ni][r];
      }
    }
  }
}

// ---------------- 128x256 BK=64 ring-3 GEMM (proj). DO NOT TOUCH ----------------
template<int OUT_BF16>
__global__ __launch_bounds__(512) void k_gemm128b(const unsigned short* __restrict__ A,
                                                  const unsigned short* __restrict__ B,
                                                  void* __restrict__ Cout,
                                                  int M, int N, int K, int nbx) {
  extern __shared__ __align__(16) char lds[];  // 3 slots x (A 16KB + B 32KB)
  const int tid = threadIdx.x, lane = tid & 63, wid = tid >> 6;
  const int lr = lane & 15, lg = lane >> 4;
  const int wr = wid >> 2, wcn = wid & 3;

  const int nwg = gridDim.x, cpx = nwg >> 3;
  const int id = (int)blockIdx.x;
  const int sid = (id & 7) * cpx + (id >> 3);
  const int by = sid / nbx, bx = sid - by * nbx;

  const unsigned short* Ab = A + (size_t)by * 128 * K;
  const unsigned short* Bb = B + (size_t)bx * 256 * K;

  const int trow = tid >> 3;
  const int tc   = tid & 7;
  const int csw  = (((tc * 16) ^ ((trow & 7) << 4)) >> 1);
  const unsigned short* pA = Ab + (size_t)trow * K + csw;
  const unsigned short* pB = Bb + (size_t)trow * K + csw;

  const int arb = (wr * 64 + lr) * 128;
  const int brb = 16384 + (wcn * 64 + lr) * 128;
  const int ch0 = (lg * 16) ^ ((lr & 7) << 4);
  const int ch1 = (64 + lg * 16) ^ ((lr & 7) << 4);

  f32x4 acc[4][4];
#pragma unroll
  for (int mi = 0; mi < 4; ++mi)
#pragma unroll
    for (int ni = 0; ni < 4; ++ni)
#pragma unroll
      for (int r = 0; r < 4; ++r) acc[mi][ni][r] = 0.f;

#define STAGE(t_, sl_) do {                                                            \
    const unsigned short* at_ = pA + (size_t)(t_) * 64;                                \
    const unsigned short* bt_ = pB + (size_t)(t_) * 64;                                \
    char* sb_ = lds + (sl_) * 49152;                                                   \
    _Pragma("unroll") for (int i = 0; i < 2; ++i)                                      \
      __builtin_amdgcn_global_load_lds((gbl_u32*)(at_ + (size_t)i * 64 * K),           \
          (lds_u32*)(sb_ + i * 8192 + wid * 1024), 16, 0, 0);                          \
    _Pragma("unroll") for (int j = 0; j < 4; ++j)                                      \
      __builtin_amdgcn_global_load_lds((gbl_u32*)(bt_ + (size_t)j * 64 * K),           \
          (lds_u32*)(sb_ + 16384 + j * 8192 + wid * 1024), 16, 0, 0);                  \
  } while (0)

#define COMPUTE(sl_) do {                                                              \
    const char* sb_ = lds + (sl_) * 49152;                                             \
    short8 afr[4][2], bfr[4][2];                                                       \
    _Pragma("unroll") for (int mi = 0; mi < 4; ++mi) {                                 \
      afr[mi][0] = *reinterpret_cast<const short8*>(sb_ + arb + mi * 2048 + ch0);      \
      afr[mi][1] = *reinterpret_cast<const short8*>(sb_ + arb + mi * 2048 + ch1);      \
    }                                                                                  \
    _Pragma("unroll") for (int ni = 0; ni < 4; ++ni) {                                 \
      bfr[ni][0] = *reinterpret_cast<const short8*>(sb_ + brb + ni * 2048 + ch0);      \
      bfr[ni][1] = *reinterpret_cast<const short8*>(sb_ + brb + ni * 2048 + ch1);      \
    }                                                                                  \
    __builtin_amdgcn_s_setprio(1);                                                     \
    _Pragma("unroll") for (int mi = 0; mi < 4; ++mi)                                   \
      _Pragma("unroll") for (int ni = 0; ni < 4; ++ni) {                               \
        f32x4 a_ = acc[mi][ni];                                                        \
        a_ = __builtin_amdgcn_mfma_f32_16x16x32_bf16(afr[mi][0], bfr[ni][0], a_, 0, 0, 0); \
        a_ = __builtin_amdgcn_mfma_f32_16x16x32_bf16(afr[mi][1], bfr[ni][1], a_, 0, 0, 0); \
        acc[mi][ni] = a_;                                                              \
      }                                                                                \
    __builtin_amdgcn_s_setprio(0);                                                     \
  } while (0)

#define WAITBAR(n) do {                                                                \
    asm volatile("s_waitcnt vmcnt(" #n ")" ::: "memory");                              \
    __builtin_amdgcn_s_barrier();                                                      \
    asm volatile("" ::: "memory");                                                     \
  } while (0)

  const int nt = K >> 6;
  STAGE(0, 0); STAGE(1, 1);
  int sc = 0, ss = 2;
  for (int t = 0; t < nt - 2; ++t) {
    WAITBAR(6);
    STAGE(t + 2, ss);
    COMPUTE(sc);
    sc = (sc == 2) ? 0 : sc + 1;
    ss = (ss == 2) ? 0 : ss + 1;
  }
  WAITBAR(6);
  COMPUTE(sc);
  sc = (sc == 2) ? 0 : sc + 1;
  WAITBAR(0);
  COMPUTE(sc);

#undef STAGE
#undef COMPUTE
#undef WAITBAR

#pragma unroll
  for (int mi = 0; mi < 4; ++mi) {
    const int row0c = by * 128 + wr * 64 + mi * 16 + lg * 4;
#pragma unroll
    for (int ni = 0; ni < 4; ++ni) {
      const int col = bx * 256 + wcn * 64 + ni * 16 + lr;
#pragma unroll
      for (int r = 0; r < 4; ++r) {
        size_t idx = (size_t)(row0c + r) * N + col;
        if (OUT_BF16) ((unsigned short*)Cout)[idx] = f2bf(acc[mi][ni][r]);
        else          ((float*)Cout)[idx] = acc[mi][ni][r];
      }
    }
  }
}

// ---------------- RoPE + RMSNorm (Q,K heads) fused with V transpose ----------------
#define NRB ((NB * T_SEQ * (NHQ + NHKV)) / 4)
__global__ __launch_bounds__(256) void k_rope_vt(const unsigned short* __restrict__ qkv,
                                                 const float* __restrict__ tbl,
                                                 unsigned short* __restrict__ Qo,
                                                 unsigned short* __restrict__ Ko,
                                                 unsigned short* __restrict__ Vt) {
  __shared__ unsigned short tile[64][65];
  if ((int)blockIdx.x < NRB) {
    const int lane = threadIdx.x & 63, wid = threadIdx.x >> 6;
    const int job = blockIdx.x * 4 + wid;
    const int row = job / 20;
    const int hh  = job - row * 20;
    const int b = row >> 11, t = row & (T_SEQ - 1);
    const unsigned short* src;
    unsigned short* dst;
    float scale;
    if (hh < NHQ) {
      src = qkv + (size_t)row * QKVN + hh * DHD;
      dst = Qo + (((size_t)b * NHQ + hh) * T_SEQ + t) * DHD;
      scale = 0.1275173019f;  // log2(e)/sqrt(128)
    } else {
      int h = hh - NHQ;
      src = qkv + (size_t)row * QKVN + CDIM + h * DHD;
      dst = Ko + (((size_t)b * NHKV + h) * T_SEQ + t) * DHD;
      scale = 1.f;
    }
    unsigned int pr = *reinterpret_cast<const unsigned int*>(src + lane * 2);
    float xe = bf2f(pr & 0xffffu), xo = bf2f(pr >> 16);
    float c = tbl[t * 64 + lane], s = tbl[T_SEQ * 64 + t * 64 + lane];
    float e = xe * c - xo * s;
    float o = xo * c + xe * s;
    float ss = e * e + o * o;
#pragma unroll
    for (int off = 1; off < 64; off <<= 1) ss += __shfl_xor(ss, off);
    float rn = rsqrtf(ss * (1.f / 128.f) + 1.1920929e-07f) * scale;
    unsigned short eb = f2bf(e * rn), ob = f2bf(o * rn);
    *reinterpret_cast<unsigned int*>(dst + lane * 2) = ((unsigned int)ob << 16) | eb;
  } else {
    const int blk = (int)blockIdx.x - NRB;
    const int dt = blk & 1;
    const int tt = (blk >> 1) & 31;
    const int h = (blk >> 6) & 3;
    const int b = blk >> 8;
    const int t0 = tt * 64, d0 = dt * 64;
#pragma unroll
    for (int i = 0; i < 16; ++i) {
      int idx = i * 256 + threadIdx.x;
      int tl = idx >> 6, dl = idx & 63;
      tile[tl][dl] = qkv[(size_t)(b * T_SEQ + t0 + tl) * QKVN + (CDIM + NHKV * DHD) + h * DHD + d0 + dl];
    }
    __syncthreads();
#pragma unroll
    for (int i = 0; i < 16; ++i) {
      int idx = i * 256 + threadIdx.x;
      int dl = idx >> 6, tl = idx & 63;
      Vt[((size_t)(b * NHKV + h) * DHD + d0 + dl) * T_SEQ + t0 + tl] = tile[tl][dl];
    }
  }
}

// ---------------- windowed causal flash attention, LDS-staged K/V ----------------
// R12 structure; R15: staging ring 3 -> 4 slots, prefetch depth 2 (vmcnt(4)
// steady-state). Slot(t+2) = slot(t-2): reads done before barrier(t-1) < stage.
__global__ __launch_bounds__(512) void k_attn(const unsigned short* __restrict__ Q,
                                              const unsigned short* __restrict__ K,
                                              const unsigned short* __restrict__ Vt,
                                              unsigned short* __restrict__ Y) {
  __shared__ __align__(16) char lds[65536];  // 4 x 16KB ring; reused for epilogue
  const int tid = threadIdx.x, lane = tid & 63, wid = tid >> 6;
  const int l31 = lane & 31, hi = lane >> 5;

  const int id = (int)blockIdx.x;
  const int sid = (id & 7) * 32 + (id >> 3);
  const int qt = sid & 7;
  const int h = (sid >> 3) & 15;
  const int b = sid >> 7;
  const int hkv = h >> 2;
  const int q0 = qt * 256;
  const int q0g = q0 + wid * 32;

  const unsigned short* Qp = Q + (((size_t)b * NHQ + h) * T_SEQ + q0g) * DHD;
  const char* Kbyte = (const char*)(K + ((size_t)b * NHKV + hkv) * T_SEQ * DHD);
  const char* Vbyte = (const char*)(Vt + ((size_t)b * NHKV + hkv) * DHD * T_SEQ);

  const int ksrc = (tid >> 4) * 256 + (((tid & 15) * 16) ^ (((tid >> 4) & 7) << 4));
  const int vsrc = (tid >> 2) * 4096 + (((tid & 3) * 16) ^ (((tid >> 2) & 3) << 4));

  const int ksw = (l31 & 7) << 4;
  const int vsw = (l31 & 3) << 4;

#define STAGEKV(k0_, sb_) do {                                                           \
    const char* kt_ = Kbyte + (size_t)(k0_) * 256;                                       \
    const char* vt_ = Vbyte + (size_t)(k0_) * 2;                                         \
    __builtin_amdgcn_global_load_lds((gbl_u32*)(kt_ + ksrc),                             \
        (lds_u32*)(lds + (sb_) + wid * 1024), 16, 0, 0);                                 \
    __builtin_amdgcn_global_load_lds((gbl_u32*)(vt_ + vsrc),                             \
        (lds_u32*)(lds + (sb_) + 8192 + wid * 1024), 16, 0, 0);                          \
  } while (0)

  const int kt0 = (q0 >= SWIN) ? ((q0 - (SWIN - 1)) >> 5) : 0;
  const int kth = (q0 + 255) >> 5;

  STAGEKV(kt0 * 32, (kt0 & 3) * 16384);
  STAGEKV((kt0 + 1) * 32, ((kt0 + 1) & 3) * 16384);

  short8 qf[8];
#pragma unroll
  for (int ds = 0; ds < 8; ++ds)
    qf[ds] = *reinterpret_cast<const short8*>(Qp + (size_t)l31 * DHD + ds * 16 + hi * 8);

  f32x16 accO[4];
#pragma unroll
  for (int dt = 0; dt < 4; ++dt)
#pragma unroll
    for (int r = 0; r < 16; ++r) accO[dt][r] = 0.f;
  float m = -1e30f, l = 0.f;
  const int qg = q0g + l31;

  for (int t = kt0; t <= kth; ++t) {
    if (t + 2 <= kth) {
      STAGEKV((t + 2) * 32, ((t + 2) & 3) * 16384);
      asm volatile("s_waitcnt vmcnt(4)" ::: "memory");
    } else if (t + 1 <= kth) {
      asm volatile("s_waitcnt vmcnt(2)" ::: "memory");
    } else {
      asm volatile("s_waitcnt vmcnt(0)" ::: "memory");
    }
    __builtin_amdgcn_s_barrier();

    const int k0 = t * 32;
    if (k0 <= q0g && k0 + 31 >= q0g - (SWIN - 1)) {
      const char* kbase = lds + (t & 3) * 16384;
      const char* vbase = kbase + 8192;

      short8 kf[8];
#pragma unroll
      for (int ds = 0; ds < 8; ++ds)
        kf[ds] = *reinterpret_cast<const short8*>(kbase + l31 * 256 + ((ds * 32 + hi * 16) ^ ksw));

      f32x16 s;
#pragma unroll
      for (int r = 0; r < 16; ++r) s[r] = 0.f;
      __builtin_amdgcn_s_setprio(1);
#pragma unroll
      for (int ds = 0; ds < 8; ++ds)
        s = __builtin_amdgcn_mfma_f32_32x32x16_bf16(kf[ds], qf[ds], s, 0, 0, 0);
      __builtin_amdgcn_s_setprio(0);

      if (k0 < q0g - 480 || k0 >= q0g) {
#pragma unroll
        for (int r = 0; r < 16; ++r) {
          int kk = k0 + (r & 3) + 8 * (r >> 2) + 4 * hi;
          if (kk > qg || qg - kk >= SWIN) s[r] = -1e30f;
        }
      }

      float mx[8];
#pragma unroll
      for (int j = 0; j < 8; ++j) mx[j] = fmaxf(s[2 * j], s[2 * j + 1]);
      float a0 = fmaxf(mx[0], mx[1]), a1 = fmaxf(mx[2], mx[3]);
      float a2 = fmaxf(mx[4], mx[5]), a3 = fmaxf(mx[6], mx[7]);
      float tmax = fmaxf(fmaxf(a0, a1), fmaxf(a2, a3));
      tmax = fmaxf(tmax, __shfl_xor(tmax, 32));

      float mn = m;
      if (!__all(tmax <= m + 8.f)) {
        mn = fmaxf(m, tmax);
        float alpha = exp2_fast(m - mn);
        l *= alpha;
#pragma unroll
        for (int dt = 0; dt < 4; ++dt)
#pragma unroll
          for (int r = 0; r < 16; ++r) accO[dt][r] *= alpha;
        m = mn;
      }

#pragma unroll
      for (int r = 0; r < 16; ++r) s[r] = exp2_fast(s[r] - mn);
      float sx[8];
#pragma unroll
      for (int j = 0; j < 8; ++j) sx[j] = s[2 * j] + s[2 * j + 1];
      float b0 = sx[0] + sx[1], b1 = sx[2] + sx[3], b2 = sx[4] + sx[5], b3 = sx[6] + sx[7];
      float ps = (b0 + b1) + (b2 + b3);
      ps += __shfl_xor(ps, 32);
      l += ps;

      unsigned int w[8];
#pragma unroll
      for (int j = 0; j < 8; ++j)
        asm("v_cvt_pk_bf16_f32 %0, %1, %2" : "=v"(w[j]) : "v"(s[2 * j]), "v"(s[2 * j + 1]));
      asm("v_permlane32_swap_b32 %0, %1" : "+v"(w[0]), "+v"(w[2]));
      asm("v_permlane32_swap_b32 %0, %1" : "+v"(w[1]), "+v"(w[3]));
      asm("v_permlane32_swap_b32 %0, %1" : "+v"(w[4]), "+v"(w[6]));
      asm("v_permlane32_swap_b32 %0, %1" : "+v"(w[5]), "+v"(w[7]));
      u32x4 p0 = {w[0], w[1], w[2], w[3]};
      u32x4 p1 = {w[4], w[5], w[6], w[7]};
      short8 pf0 = __builtin_bit_cast(short8, p0);
      short8 pf1 = __builtin_bit_cast(short8, p1);

      __builtin_amdgcn_s_setprio(1);
#pragma unroll
      for (int dt = 0; dt < 4; ++dt) {
        const char* vrow = vbase + (dt * 2048 + l31 * 64);
        short8 vf0 = *reinterpret_cast<const short8*>(vrow + ((hi * 16) ^ vsw));
        short8 vf1 = *reinterpret_cast<const short8*>(vrow + ((32 + hi * 16) ^ vsw));
        accO[dt] = __builtin_amdgcn_mfma_f32_32x32x16_bf16(vf0, pf0, accO[dt], 0, 0, 0);
        accO[dt] = __builtin_amdgcn_mfma_f32_32x32x16_bf16(vf1, pf1, accO[dt], 0, 0, 0);
      }
      __builtin_amdgcn_s_setprio(0);
    }
  }
#undef STAGEKV

  __syncthreads();

  float inv = 1.f / l;
  char* obc = lds + wid * 8192;
#pragma unroll
  for (int dt = 0; dt < 4; ++dt)
#pragma unroll
    for (int j = 0; j < 8; ++j) {
      float a = accO[dt][2 * j] * inv, c = accO[dt][2 * j + 1] * inv;
      unsigned int wv;
      asm("v_cvt_pk_bf16_f32 %0, %1, %2" : "=v"(wv) : "v"(a), "v"(c));
      int d = dt * 32 + 2 * (j & 1) + 8 * (j >> 1) + 4 * hi;
      *reinterpret_cast<unsigned int*>(obc + l31 * 256 + ((d * 2) ^ ksw)) = wv;
    }
#pragma unroll
  for (int i = 0; i < 8; ++i) {
    int chunk = i * 64 + lane;
    int row = chunk >> 4, c8 = chunk & 15;
    short8 v = *reinterpret_cast<const short8*>(obc + row * 256 + ((c8 * 16) ^ ((row & 7) << 4)));
    *reinterpret_cast<short8*>(Y + ((size_t)b * T_SEQ + q0g + row) * CDIM + h * DHD + c8 * 8) = v;
  }
}

extern "C" void kernel_launch(void* const* d_in, const int* in_sizes, int n_in,
                              void* d_out, int out_size, void* d_ws, size_t ws_size,
                              hipStream_t stream) {
  const float* x     = (const float*)d_in[0];
  const float* wqkv  = (const float*)d_in[1];
  const float* wproj = (const float*)d_in[2];
  float* out = (float*)d_out;

  char* ws = (char*)d_ws;
  unsigned short* xb     = (unsigned short*)(ws + 0);         // 16 MB (reused as y)
  unsigned short* wqkvb  = (unsigned short*)(ws + 16777216);  // 12 MB
  unsigned short* wprojb = (unsigned short*)(ws + 29360128);  // 8 MB
  unsigned short* qkvb   = (unsigned short*)(ws + 37748736);  // 24 MB
  unsigned short* Qb     = (unsigned short*)(ws + 62914560);  // 16 MB
  unsigned short* Kb     = (unsigned short*)(ws + 79691776);  // 4 MB
  unsigned short* Vtb    = (unsigned short*)(ws + 83886080);  // 4 MB
  float* tbl             = (float*)(ws + 88080384);           // 1 MB
  unsigned short* yb     = xb;

  k_f2bf3t<<<2048, 256, 0, stream>>>(x, xb, (NB * T_SEQ * CDIM) / 4,
                                     wqkv, wqkvb, (QKVN * CDIM) / 4,
                                     wproj, wprojb, (CDIM * CDIM) / 4, tbl);

  k_gemm192<1><<<256, 512, 114688, stream>>>(
      xb, wqkvb, qkvb, NB * T_SEQ, QKVN, CDIM, QKVN / 192);
  k_rope_vt<<<NRB + 512, 256, 0, stream>>>(qkvb, tbl, Qb, Kb, Vtb);
  k_attn<<<NB * NHQ * (T_SEQ / 256), 512, 0, stream>>>(Qb, Kb, Vtb, yb);
  k_gemm128b<0><<<256, 512, 147456, stream>>>(
      yb, wprojb, out, NB * T_SEQ, CDIM, CDIM, CDIM / 256);
}